// Round 1
// baseline (441.840 us; speedup 1.0000x reference)
//
#include <hip/hip_runtime.h>
#include <hip/hip_bf16.h>

#define NN   2000
#define NE   32000
#define EMBD 768
#define NH   4
#define HID  384
#define FTD  768
#define NEG  0.2f

__device__ inline float wred(float v){
#pragma unroll
  for (int o = 32; o > 0; o >>= 1) v += __shfl_down(v, o, 64);
  return v;
}

// ---- CSR build -------------------------------------------------------------
__global__ void k_count(const int* __restrict__ dst, int* __restrict__ counts){
  int e = blockIdx.x * blockDim.x + threadIdx.x;
  if (e < NE) atomicAdd(&counts[dst[e]], 1);
}

__global__ void k_scan(const int* __restrict__ counts, int* __restrict__ offsets,
                       int* __restrict__ cursor){
  __shared__ int s[1024];
  int t = threadIdx.x;
  int a = (2*t   < NN) ? counts[2*t  ] : 0;
  int b = (2*t+1 < NN) ? counts[2*t+1] : 0;
  s[t] = a + b;
  __syncthreads();
  for (int off = 1; off < 1024; off <<= 1){
    int v = (t >= off) ? s[t-off] : 0;
    __syncthreads();
    s[t] += v;
    __syncthreads();
  }
  int base = (t > 0) ? s[t-1] : 0;
  if (2*t < NN){ offsets[2*t] = base; cursor[2*t] = base; }
  if (2*t+1 < NN){ offsets[2*t+1] = base + a; cursor[2*t+1] = base + a; }
  if (2*t == NN) offsets[NN] = base;
}

__global__ void k_fill(const int* __restrict__ dst, int* __restrict__ cursor,
                       int* __restrict__ csr){
  int e = blockIdx.x * blockDim.x + threadIdx.x;
  if (e < NE){
    int p = atomicAdd(&cursor[dst[e]], 1);
    csr[p] = e;
  }
}

// deterministic order within each bucket (so float sums are replay-stable)
__global__ void k_sort(const int* __restrict__ offsets, int* __restrict__ csr){
  int n = blockIdx.x * blockDim.x + threadIdx.x;
  if (n >= NN) return;
  int lo = offsets[n], hi = offsets[n+1];
  for (int i = lo+1; i < hi; ++i){
    int v = csr[i], j = i-1;
    while (j >= lo && csr[j] > v){ csr[j+1] = csr[j]; --j; }
    csr[j+1] = v;
  }
}

// ---- weight collapses ------------------------------------------------------
// out[k,h] = sum_c W[k, h*C+c] * a[h,c]    (grid = K*NH waves of 64)
__global__ void k_collapse(const float* __restrict__ W, const float* __restrict__ a,
                           float* __restrict__ out, int C){
  int wid = blockIdx.x;
  int k = wid >> 2, h = wid & 3;
  int lane = threadIdx.x;
  const float* wr = W + (size_t)k * (NH*C) + (size_t)h * C;
  const float* ar = a + (size_t)h * C;
  float acc = 0.f;
  for (int c = lane; c < C; c += 64) acc += wr[c] * ar[c];
  acc = wred(acc);
  if (lane == 0) out[k*NH + h] = acc;
}

// out[r,h] = sum_k A[r,k] * wv[k,h]        (grid = R*NH waves of 64)
__global__ void k_rowdot(const float* __restrict__ A, const float* __restrict__ wv,
                         float* __restrict__ out, int K){
  int wid = blockIdx.x;
  int r = wid >> 2, h = wid & 3;
  int lane = threadIdx.x;
  const float* ar = A + (size_t)r * K;
  float acc = 0.f;
  for (int k = lane; k < K; k += 64) acc += ar[k] * wv[k*NH + h];
  acc = wred(acc);
  if (lane == 0) out[r*NH + h] = acc;
}

// ---- f32 tiled GEMM: C[M,Nd] = A[M,K] @ B[K,Nd] ----------------------------
__global__ __launch_bounds__(256) void k_gemm(const float* __restrict__ A,
                                              const float* __restrict__ B,
                                              float* __restrict__ C,
                                              int M, int Nd, int K){
  __shared__ float As[16][68];
  __shared__ float Bs[16][68];
  int t = threadIdx.x;
  int bm = blockIdx.y * 64, bn = blockIdx.x * 64;
  int tm = t >> 4, tn = t & 15;
  float acc[4][4] = {};
  int arow = t >> 2, acol = (t & 3) * 4;
  int brow = t >> 4, bcol = (t & 15) * 4;
  for (int k0 = 0; k0 < K; k0 += 16){
    float4 av = make_float4(0.f, 0.f, 0.f, 0.f);
    int gm = bm + arow;
    if (gm < M) av = *(const float4*)&A[(size_t)gm*K + k0 + acol];
    As[acol+0][arow] = av.x; As[acol+1][arow] = av.y;
    As[acol+2][arow] = av.z; As[acol+3][arow] = av.w;
    *(float4*)&Bs[brow][bcol] = *(const float4*)&B[(size_t)(k0+brow)*Nd + bn + bcol];
    __syncthreads();
#pragma unroll
    for (int k = 0; k < 16; ++k){
      float4 a4 = *(const float4*)&As[k][tm*4];
      float4 b4 = *(const float4*)&Bs[k][tn*4];
      acc[0][0] += a4.x*b4.x; acc[0][1] += a4.x*b4.y; acc[0][2] += a4.x*b4.z; acc[0][3] += a4.x*b4.w;
      acc[1][0] += a4.y*b4.x; acc[1][1] += a4.y*b4.y; acc[1][2] += a4.y*b4.z; acc[1][3] += a4.y*b4.w;
      acc[2][0] += a4.z*b4.x; acc[2][1] += a4.z*b4.y; acc[2][2] += a4.z*b4.z; acc[2][3] += a4.z*b4.w;
      acc[3][0] += a4.w*b4.x; acc[3][1] += a4.w*b4.y; acc[3][2] += a4.w*b4.z; acc[3][3] += a4.w*b4.w;
    }
    __syncthreads();
  }
#pragma unroll
  for (int i = 0; i < 4; ++i){
    int gm = bm + tm*4 + i;
    if (gm < M){
      float4 r; r.x = acc[i][0]; r.y = acc[i][1]; r.z = acc[i][2]; r.w = acc[i][3];
      *(float4*)&C[(size_t)gm*Nd + bn + tn*4] = r;
    }
  }
}

// ---- gathers ---------------------------------------------------------------
// hx1[n,:] = xh1[x[n,0],:] + xh1[x[n,1],:]   (float4 granularity, row = 384 float4)
__global__ void k_hx1(const int* __restrict__ x, const float* __restrict__ xh1,
                      float* __restrict__ hx1){
  int i = blockIdx.x * blockDim.x + threadIdx.x;
  if (i >= NN * 384) return;
  int n = i / 384, j = i - n * 384;
  int a = x[2*n], b = x[2*n+1];
  float4 u = ((const float4*)xh1)[a*384 + j];
  float4 v = ((const float4*)xh1)[b*384 + j];
  float4 r; r.x = u.x+v.x; r.y = u.y+v.y; r.z = u.z+v.z; r.w = u.w+v.w;
  ((float4*)hx1)[i] = r;
}

__global__ void k_nodealpha(const int* __restrict__ x, const float* __restrict__ ts,
                            const float* __restrict__ td, float* __restrict__ asrc,
                            float* __restrict__ adst){
  int i = blockIdx.x * blockDim.x + threadIdx.x;
  if (i >= NN * NH) return;
  int n = i >> 2, h = i & 3;
  int a = x[2*n], b = x[2*n+1];
  asrc[i] = ts[a*NH+h] + ts[b*NH+h];
  adst[i] = td[a*NH+h] + td[b*NH+h];
}

__global__ void k_edgealpha(const int* __restrict__ ea, const float* __restrict__ ew1,
                            const float* __restrict__ ew2, float* __restrict__ ae1e,
                            float* __restrict__ ae2e){
  int i = blockIdx.x * blockDim.x + threadIdx.x;
  if (i >= NE * NH) return;
  int e = i >> 2, h = i & 3;
  int a = ea[2*e], b = ea[2*e+1];
  ae1e[i] = ew1[a*NH+h] + ew1[b*NH+h];
  ae2e[i] = ew2[a*NH+h] + ew2[b*NH+h];
}

// ---- segment softmax (per (node,head) thread; CSR order => deterministic) --
// att buffer: in = raw edge alpha_e contribution, out = normalized attention
__global__ void k_softmax(const int* __restrict__ offsets, const int* __restrict__ csr,
                          const int* __restrict__ srcv, const float* __restrict__ asrc,
                          const float* __restrict__ adst, float* __restrict__ att,
                          float* __restrict__ attl){
  int i = blockIdx.x * blockDim.x + threadIdx.x;
  if (i >= NN * NH) return;
  int n = i >> 2, h = i & 3;
  int lo = offsets[n], hi = offsets[n+1];
  float ad = adst[n*NH + h];
  float sum_ae = 0.f, mx = -1e30f;
  for (int p = lo; p < hi; ++p){
    int e = csr[p];
    float ae = att[e*NH + h];
    sum_ae += ae;
    float al = asrc[srcv[e]*NH + h] + ad + ae;
    al = (al > 0.f) ? al : NEG * al;
    att[e*NH + h] = al;
    mx = fmaxf(mx, al);
  }
  float degf = (float)(hi - lo);
  float all_ = asrc[n*NH + h] + ad + sum_ae / fmaxf(degf, 1.f);
  all_ = (all_ > 0.f) ? all_ : NEG * all_;
  mx = fmaxf(mx, all_);
  float den = 0.f;
  for (int p = lo; p < hi; ++p){
    int e = csr[p];
    float ex = expf(att[e*NH + h] - mx);
    att[e*NH + h] = ex;
    den += ex;
  }
  float exl = expf(all_ - mx);
  den += exl;
  float inv = 1.f / den;
  for (int p = lo; p < hi; ++p){ int e = csr[p]; att[e*NH + h] *= inv; }
  attl[n*NH + h] = exl * inv;
}

// ---- attention-weighted aggregation + head mean + bias (+relu) -------------
// block = C threads, grid = NN. out[n,c] = 0.25*sum_h sum_e att*hx[src,h*C+c] + bias
__global__ void k_agg(const int* __restrict__ offsets, const int* __restrict__ csr,
                      const int* __restrict__ srcv, const float* __restrict__ att_e,
                      const float* __restrict__ att_l, const float* __restrict__ hx,
                      const float* __restrict__ bias, float* __restrict__ out,
                      int C, int relu){
  int n = blockIdx.x, c = threadIdx.x;
  int lo = offsets[n], hi = offsets[n+1];
  __shared__ float satt[256];
  __shared__ int   ssrc[64];
  float acc = 0.f;
  int HC = 4 * C;
  for (int base = lo; base < hi; base += 64){
    int cnt = min(64, hi - base);
    __syncthreads();
    if (c < cnt*4) satt[c] = att_e[csr[base + (c >> 2)]*4 + (c & 3)];
    if (c >= 256 && c < 256 + cnt) ssrc[c - 256] = srcv[csr[base + c - 256]];
    __syncthreads();
    for (int j = 0; j < cnt; ++j){
      const float* hp = &hx[ssrc[j]*HC + c];
      acc += satt[4*j+0]*hp[0] + satt[4*j+1]*hp[C] + satt[4*j+2]*hp[2*C] + satt[4*j+3]*hp[3*C];
    }
  }
  {
    const float* hp = &hx[n*HC + c];
    const float* al = &att_l[n*4];
    acc += al[0]*hp[0] + al[1]*hp[C] + al[2]*hp[2*C] + al[3]*hp[3*C];
  }
  float v = 0.25f * acc + bias[c];
  if (relu) v = fmaxf(v, 0.f);
  out[n*C + c] = v;
}

// ---------------------------------------------------------------------------
extern "C" void kernel_launch(void* const* d_in, const int* in_sizes, int n_in,
                              void* d_out, int out_size, void* d_ws, size_t ws_size,
                              hipStream_t stream){
  const int*   x     = (const int*)d_in[0];
  const int*   ei    = (const int*)d_in[1];
  const int*   ea    = (const int*)d_in[2];
  const float* x_emb = (const float*)d_in[3];
  const float* e_emb = (const float*)d_in[4];
  const float* W1    = (const float*)d_in[5];
  const float* as1   = (const float*)d_in[6];
  const float* ad1   = (const float*)d_in[7];
  const float* We1   = (const float*)d_in[8];
  const float* ae1   = (const float*)d_in[9];
  const float* b1    = (const float*)d_in[10];
  const float* W2    = (const float*)d_in[11];
  const float* as2   = (const float*)d_in[12];
  const float* ad2   = (const float*)d_in[13];
  const float* We2   = (const float*)d_in[14];
  const float* ae2   = (const float*)d_in[15];
  const float* b2    = (const float*)d_in[16];
  const int* srcv = ei;
  const int* dstv = ei + NE;
  float* out = (float*)d_out;

  char* p = (char*)d_ws;
  auto take = [&](size_t n){ void* q = (void*)p; p += (n + 255) & ~(size_t)255; return q; };
  int*   counts  = (int*)take(NN*4);
  int*   offsets = (int*)take((NN+1)*4);
  int*   cursor  = (int*)take(NN*4);
  int*   csr     = (int*)take(NE*4);
  float* wa_s1   = (float*)take(EMBD*NH*4);
  float* wa_d1   = (float*)take(EMBD*NH*4);
  float* we_a1   = (float*)take(EMBD*NH*4);
  float* wa_s2   = (float*)take(HID*NH*4);
  float* wa_d2   = (float*)take(HID*NH*4);
  float* we_a2   = (float*)take(EMBD*NH*4);
  float* xh1     = (float*)take((size_t)178*NH*HID*4);
  float* xa_s1   = (float*)take(178*NH*4);
  float* xa_d1   = (float*)take(178*NH*4);
  float* ew1     = (float*)take(18*NH*4);
  float* ew2     = (float*)take(18*NH*4);
  float* hx1     = (float*)take((size_t)NN*NH*HID*4);
  float* asrc1   = (float*)take(NN*NH*4);
  float* adst1   = (float*)take(NN*NH*4);
  float* att1    = (float*)take((size_t)NE*NH*4);
  float* att2    = (float*)take((size_t)NE*NH*4);
  float* attl1   = (float*)take(NN*NH*4);
  float* attl2   = (float*)take(NN*NH*4);
  float* hact    = (float*)take((size_t)NN*HID*4);
  float* hx2     = (float*)take((size_t)NN*NH*FTD*4);
  float* asrc2   = (float*)take(NN*NH*4);
  float* adst2   = (float*)take(NN*NH*4);

  // CSR (deterministic after in-bucket sort)
  hipMemsetAsync(counts, 0, NN*4, stream);
  k_count<<<(NE+255)/256, 256, 0, stream>>>(dstv, counts);
  k_scan<<<1, 1024, 0, stream>>>(counts, offsets, cursor);
  k_fill<<<(NE+255)/256, 256, 0, stream>>>(dstv, cursor, csr);
  k_sort<<<(NN+255)/256, 256, 0, stream>>>(offsets, csr);

  // weight collapses: wa[k,h] = sum_c W[k,h*C+c]*a[h,c]
  k_collapse<<<EMBD*NH, 64, 0, stream>>>(W1,  as1, wa_s1, HID);
  k_collapse<<<EMBD*NH, 64, 0, stream>>>(W1,  ad1, wa_d1, HID);
  k_collapse<<<EMBD*NH, 64, 0, stream>>>(We1, ae1, we_a1, HID);
  k_collapse<<<HID*NH,  64, 0, stream>>>(W2,  as2, wa_s2, FTD);
  k_collapse<<<HID*NH,  64, 0, stream>>>(W2,  ad2, wa_d2, FTD);
  k_collapse<<<EMBD*NH, 64, 0, stream>>>(We2, ae2, we_a2, FTD);

  // tiny tables over the 178 node-embedding rows / 18 edge-embedding rows
  k_rowdot<<<178*NH, 64, 0, stream>>>(x_emb, wa_s1, xa_s1, EMBD);
  k_rowdot<<<178*NH, 64, 0, stream>>>(x_emb, wa_d1, xa_d1, EMBD);
  k_rowdot<<<18*NH,  64, 0, stream>>>(e_emb, we_a1, ew1,   EMBD);
  k_rowdot<<<18*NH,  64, 0, stream>>>(e_emb, we_a2, ew2,   EMBD);

  // xh1 = x_emb @ W1  [178,1536]
  { dim3 g(24, 3); k_gemm<<<g, 256, 0, stream>>>(x_emb, W1, xh1, 178, NH*HID, EMBD); }

  // layer-1 per-node/per-edge terms
  k_hx1<<<(NN*384+255)/256, 256, 0, stream>>>(x, xh1, hx1);
  k_nodealpha<<<(NN*NH+255)/256, 256, 0, stream>>>(x, xa_s1, xa_d1, asrc1, adst1);
  k_edgealpha<<<(NE*NH+255)/256, 256, 0, stream>>>(ea, ew1, ew2, att1, att2);

  // layer 1: softmax + aggregate (+bias +relu) -> hact [2000,384]
  k_softmax<<<(NN*NH+255)/256, 256, 0, stream>>>(offsets, csr, srcv, asrc1, adst1, att1, attl1);
  k_agg<<<NN, HID, 0, stream>>>(offsets, csr, srcv, att1, attl1, hx1, b1, hact, HID, 1);

  // layer 2: hx2 = hact @ W2 [2000,3072]; alpha terms from hact
  { dim3 g(48, 32); k_gemm<<<g, 256, 0, stream>>>(hact, W2, hx2, NN, NH*FTD, HID); }
  k_rowdot<<<NN*NH, 64, 0, stream>>>(hact, wa_s2, asrc2, HID);
  k_rowdot<<<NN*NH, 64, 0, stream>>>(hact, wa_d2, adst2, HID);

  k_softmax<<<(NN*NH+255)/256, 256, 0, stream>>>(offsets, csr, srcv, asrc2, adst2, att2, attl2);
  k_agg<<<NN, FTD, 0, stream>>>(offsets, csr, srcv, att2, attl2, hx2, b2, out, FTD, 0);
}

// Round 2
// 302.850 us; speedup vs baseline: 1.4589x; 1.4589x over previous
//
#include <hip/hip_runtime.h>
#include <hip/hip_bf16.h>

#define NN   2000
#define NE   32000
#define EMBD 768
#define NH   4
#define HID  384
#define FTD  768
#define NEG  0.2f
#define DCAP 1024

#define GM 2000
#define GN 768
#define GK 1536
#define SPLITK 6
#define KSL (GK / SPLITK)   // 256

__device__ inline float wsum(float v){
#pragma unroll
  for (int o = 32; o > 0; o >>= 1) v += __shfl_xor(v, o, 64);
  return v;
}
__device__ inline float wmax(float v){
#pragma unroll
  for (int o = 32; o > 0; o >>= 1) v = fmaxf(v, __shfl_xor(v, o, 64));
  return v;
}

// ---- CSR build -------------------------------------------------------------
__global__ void k_count(const int* __restrict__ dst, int* __restrict__ counts){
  int e = blockIdx.x * blockDim.x + threadIdx.x;
  if (e < NE) atomicAdd(&counts[dst[e]], 1);
}

__global__ void k_scan(const int* __restrict__ counts, int* __restrict__ offsets,
                       int* __restrict__ cursor){
  __shared__ int s[1024];
  int t = threadIdx.x;
  int a = (2*t   < NN) ? counts[2*t  ] : 0;
  int b = (2*t+1 < NN) ? counts[2*t+1] : 0;
  s[t] = a + b;
  __syncthreads();
  for (int off = 1; off < 1024; off <<= 1){
    int v = (t >= off) ? s[t-off] : 0;
    __syncthreads();
    s[t] += v;
    __syncthreads();
  }
  int base = (t > 0) ? s[t-1] : 0;
  if (2*t < NN){ offsets[2*t] = base; cursor[2*t] = base; }
  if (2*t+1 < NN){ offsets[2*t+1] = base + a; cursor[2*t+1] = base + a; }
  if (2*t == NN) offsets[NN] = base;
}

__global__ void k_fill(const int* __restrict__ dst, int* __restrict__ cursor,
                       int* __restrict__ csr){
  int e = blockIdx.x * blockDim.x + threadIdx.x;
  if (e < NE){
    int p = atomicAdd(&cursor[dst[e]], 1);
    csr[p] = e;
  }
}

__global__ void k_sort(const int* __restrict__ offsets, int* __restrict__ csr){
  int n = blockIdx.x * blockDim.x + threadIdx.x;
  if (n >= NN) return;
  int lo = offsets[n], hi = offsets[n+1];
  for (int i = lo+1; i < hi; ++i){
    int v = csr[i], j = i-1;
    while (j >= lo && csr[j] > v){ csr[j+1] = csr[j]; --j; }
    csr[j+1] = v;
  }
}

// ---- prep 1: weight collapses + W2v reorder (64-thread blocks) -------------
// collapse: out[k*4+h] = sum_c W[k*(4C)+h*C+c] * a[h*C+c]
// W2v[(h*384+k)*768 + c] = W2[k*3072 + h*768 + c]
__global__ void k_prep1(const float* __restrict__ W1,  const float* __restrict__ as1,
                        const float* __restrict__ ad1, const float* __restrict__ We1,
                        const float* __restrict__ ae1, const float* __restrict__ W2,
                        const float* __restrict__ as2, const float* __restrict__ ad2,
                        const float* __restrict__ We2, const float* __restrict__ ae2,
                        float* __restrict__ wa_s1, float* __restrict__ wa_d1,
                        float* __restrict__ we_a1, float* __restrict__ wa_s2,
                        float* __restrict__ wa_d2, float* __restrict__ we_a2,
                        float* __restrict__ W2v){
  int b = blockIdx.x, lane = threadIdx.x;
  const float *W, *a; float* o; int C;
  if (b < 3072)       {          W=W1;  a=as1; o=wa_s1; C=384; }
  else if (b < 6144)  { b-=3072; W=W1;  a=ad1; o=wa_d1; C=384; }
  else if (b < 9216)  { b-=6144; W=We1; a=ae1; o=we_a1; C=384; }
  else if (b < 10752) { b-=9216; W=W2;  a=as2; o=wa_s2; C=768; }
  else if (b < 12288) { b-=10752;W=W2;  a=ad2; o=wa_d2; C=768; }
  else if (b < 15360) { b-=12288;W=We2; a=ae2; o=we_a2; C=768; }
  else {
    int gid = (b - 15360) * 64 + lane;          // < 1536*192
    if (gid < 1536*192){
      int r = gid / 192, f = gid - r*192;
      int h = r / 384, k = r - h*384;
      ((float4*)W2v)[gid] = ((const float4*)W2)[(size_t)k*768 + h*192 + f];
    }
    return;
  }
  int k = b >> 2, h = b & 3;
  const float* wr = W + (size_t)k * (4*C) + (size_t)h * C;
  const float* ar = a + (size_t)h * C;
  float acc = 0.f;
  for (int c = lane; c < C; c += 64) acc += wr[c] * ar[c];
  acc = wsum(acc);
  if (lane == 0) o[k*NH + h] = acc;
}

// ---- prep 2: table row-dots (depend on prep1) ------------------------------
__global__ void k_prep2(const float* __restrict__ x_emb, const float* __restrict__ e_emb,
                        const float* __restrict__ wa_s1, const float* __restrict__ wa_d1,
                        const float* __restrict__ we_a1, const float* __restrict__ we_a2,
                        float* __restrict__ xa_s1, float* __restrict__ xa_d1,
                        float* __restrict__ ew1, float* __restrict__ ew2){
  int b = blockIdx.x, lane = threadIdx.x;
  const float *A, *wv; float* o;
  if (b < 712)        {          A=x_emb; wv=wa_s1; o=xa_s1; }
  else if (b < 1424)  { b-=712;  A=x_emb; wv=wa_d1; o=xa_d1; }
  else if (b < 1496)  { b-=1424; A=e_emb; wv=we_a1; o=ew1; }
  else                { b-=1496; A=e_emb; wv=we_a2; o=ew2; }
  int r = b >> 2, h = b & 3;
  const float* ar = A + (size_t)r * EMBD;
  float acc = 0.f;
  for (int k = lane; k < EMBD; k += 64) acc += ar[k] * wv[k*NH + h];
  acc = wsum(acc);
  if (lane == 0) o[r*NH + h] = acc;
}

// ---- generic 64x64-tile f32 GEMM (used for xh1 = x_emb @ W1) ---------------
__global__ __launch_bounds__(256) void k_gemm(const float* __restrict__ A,
                                              const float* __restrict__ B,
                                              float* __restrict__ C,
                                              int M, int Nd, int K){
  __shared__ float As[16][68];
  __shared__ float Bs[16][68];
  int t = threadIdx.x;
  int bm = blockIdx.y * 64, bn = blockIdx.x * 64;
  int tm = t >> 4, tn = t & 15;
  float acc[4][4] = {};
  int arow = t >> 2, acol = (t & 3) * 4;
  int brow = t >> 4, bcol = (t & 15) * 4;
  for (int k0 = 0; k0 < K; k0 += 16){
    float4 av = make_float4(0.f, 0.f, 0.f, 0.f);
    int gm = bm + arow;
    if (gm < M) av = *(const float4*)&A[(size_t)gm*K + k0 + acol];
    As[acol+0][arow] = av.x; As[acol+1][arow] = av.y;
    As[acol+2][arow] = av.z; As[acol+3][arow] = av.w;
    *(float4*)&Bs[brow][bcol] = *(const float4*)&B[(size_t)(k0+brow)*Nd + bn + bcol];
    __syncthreads();
#pragma unroll
    for (int k = 0; k < 16; ++k){
      float4 a4 = *(const float4*)&As[k][tm*4];
      float4 b4 = *(const float4*)&Bs[k][tn*4];
      acc[0][0] += a4.x*b4.x; acc[0][1] += a4.x*b4.y; acc[0][2] += a4.x*b4.z; acc[0][3] += a4.x*b4.w;
      acc[1][0] += a4.y*b4.x; acc[1][1] += a4.y*b4.y; acc[1][2] += a4.y*b4.z; acc[1][3] += a4.y*b4.w;
      acc[2][0] += a4.z*b4.x; acc[2][1] += a4.z*b4.y; acc[2][2] += a4.z*b4.z; acc[2][3] += a4.z*b4.w;
      acc[3][0] += a4.w*b4.x; acc[3][1] += a4.w*b4.y; acc[3][2] += a4.w*b4.z; acc[3][3] += a4.w*b4.w;
    }
    __syncthreads();
  }
#pragma unroll
  for (int i = 0; i < 4; ++i){
    int gm = bm + tm*4 + i;
    if (gm < M){
      float4 r; r.x = acc[i][0]; r.y = acc[i][1]; r.z = acc[i][2]; r.w = acc[i][3];
      *(float4*)&C[(size_t)gm*Nd + bn + tn*4] = r;
    }
  }
}

// ---- misc fused elementwise: hx1 gather + node alpha + edge alpha ----------
__global__ void k_misc(const int* __restrict__ x, const int* __restrict__ ea,
                       const float* __restrict__ xh1, const float* __restrict__ xa_s1,
                       const float* __restrict__ xa_d1, const float* __restrict__ ew1,
                       const float* __restrict__ ew2, float* __restrict__ hx1,
                       float* __restrict__ asrc1, float* __restrict__ adst1,
                       float* __restrict__ eatt1, float* __restrict__ eatt2){
  int i = blockIdx.x * blockDim.x + threadIdx.x;
  if (i < NN*384){                      // hx1: [2000,1536] in float4 (384 f4/row)
    int n = i / 384, j = i - n*384;
    int a = x[2*n], b = x[2*n+1];
    float4 u = ((const float4*)xh1)[a*384 + j];
    float4 v = ((const float4*)xh1)[b*384 + j];
    float4 r; r.x=u.x+v.x; r.y=u.y+v.y; r.z=u.z+v.z; r.w=u.w+v.w;
    ((float4*)hx1)[i] = r;
  } else if (i < NN*384 + NN*NH){
    int i2 = i - NN*384;
    int n = i2 >> 2, h = i2 & 3;
    int a = x[2*n], b = x[2*n+1];
    asrc1[i2] = xa_s1[a*NH+h] + xa_s1[b*NH+h];
    adst1[i2] = xa_d1[a*NH+h] + xa_d1[b*NH+h];
  } else if (i < NN*384 + NN*NH + NE*NH){
    int i2 = i - NN*384 - NN*NH;
    int e = i2 >> 2, h = i2 & 3;
    int a = ea[2*e], b = ea[2*e+1];
    eatt1[i2] = ew1[a*NH+h] + ew1[b*NH+h];
    eatt2[i2] = ew2[a*NH+h] + ew2[b*NH+h];
  }
}

// ---- fused softmax (wave-per-head), weights into LDS (global fallback) -----
__device__ void gat_softmax(int n, int lo, int hi, int w, int lane, bool big,
                            const int* __restrict__ csr, const int* __restrict__ srcv,
                            const float* __restrict__ asrc, const float* __restrict__ adst,
                            float* eatt, float (*wts)[4], int* ssrc, float* wl){
  int deg = hi - lo;
  float ad_n = adst[n*NH + w];
  float as_n = asrc[n*NH + w];
  float mx = -3.4e38f, sae = 0.f;
  if (!big){
    for (int p = lo + lane; p < hi; p += 64){
      int e = csr[p]; int s = srcv[e];
      if (w == 0) ssrc[p - lo] = s;
      float ae = eatt[e*NH + w];
      float al = asrc[s*NH + w] + ad_n + ae;
      al = (al > 0.f) ? al : NEG * al;
      wts[p - lo][w] = al;
      sae += ae; mx = fmaxf(mx, al);
    }
    mx = wmax(mx); sae = wsum(sae);
    float all_ = as_n + ad_n + sae / fmaxf((float)deg, 1.f);
    all_ = (all_ > 0.f) ? all_ : NEG * all_;
    mx = fmaxf(mx, all_);
    float den = 0.f;
    for (int p = lo + lane; p < hi; p += 64){
      float xx = expf(wts[p - lo][w] - mx);
      wts[p - lo][w] = xx; den += xx;
    }
    den = wsum(den);
    float exl = expf(all_ - mx);
    den += exl;
    float inv = 1.f / den;
    for (int p = lo + lane; p < hi; p += 64) wts[p - lo][w] *= inv;
    if (lane == 0) wl[w] = exl * inv;
  } else {
    for (int p = lo + lane; p < hi; p += 64){
      int e = csr[p];
      float ae = eatt[e*NH + w];
      float al = asrc[srcv[e]*NH + w] + ad_n + ae;
      al = (al > 0.f) ? al : NEG * al;
      eatt[e*NH + w] = al;
      sae += ae; mx = fmaxf(mx, al);
    }
    mx = wmax(mx); sae = wsum(sae);
    float all_ = as_n + ad_n + sae / fmaxf((float)deg, 1.f);
    all_ = (all_ > 0.f) ? all_ : NEG * all_;
    mx = fmaxf(mx, all_);
    float den = 0.f;
    for (int p = lo + lane; p < hi; p += 64){
      int e = csr[p];
      float xx = expf(eatt[e*NH + w] - mx);
      eatt[e*NH + w] = xx; den += xx;
    }
    den = wsum(den);
    float exl = expf(all_ - mx);
    den += exl;
    float inv = 1.f / den;
    for (int p = lo + lane; p < hi; p += 64) eatt[csr[p]*NH + w] *= inv;
    if (lane == 0) wl[w] = exl * inv;
  }
}

// ---- layer-1 fused: softmax + agg (relu, bias, head-mean) + alpha2 dots ----
__global__ __launch_bounds__(384) void k_gat1(const int* __restrict__ offsets,
                      const int* __restrict__ csr, const int* __restrict__ srcv,
                      const float* __restrict__ asrc, const float* __restrict__ adst,
                      float* eatt, const float* __restrict__ hx1,
                      const float* __restrict__ b1, const float* __restrict__ wa_s2,
                      const float* __restrict__ wa_d2, float* __restrict__ hact,
                      float* __restrict__ asrc2, float* __restrict__ adst2){
  __shared__ float wts[DCAP][4];
  __shared__ int   ssrc[DCAP];
  __shared__ float wl[4];
  __shared__ float red[6][8];
  int n = blockIdx.x, t = threadIdx.x;
  int w = t >> 6, lane = t & 63;
  int lo = offsets[n], hi = offsets[n+1];
  int deg = hi - lo;
  bool big = deg > DCAP;
  if (w < 4) gat_softmax(n, lo, hi, w, lane, big, csr, srcv, asrc, adst, eatt, wts, ssrc, wl);
  __syncthreads();

  int c = t;  // 0..383
  float acc = 0.f;
  for (int j = 0; j < deg; ++j){
    int s; float w0, w1, w2, w3;
    if (big){ int e = csr[lo+j]; s = srcv[e];
      w0 = eatt[e*4+0]; w1 = eatt[e*4+1]; w2 = eatt[e*4+2]; w3 = eatt[e*4+3];
    } else { s = ssrc[j]; w0 = wts[j][0]; w1 = wts[j][1]; w2 = wts[j][2]; w3 = wts[j][3]; }
    const float* hp = hx1 + (size_t)s*1536 + c;
    acc += w0*hp[0] + w1*hp[384] + w2*hp[768] + w3*hp[1152];
  }
  {
    const float* hp = hx1 + (size_t)n*1536 + c;
    acc += wl[0]*hp[0] + wl[1]*hp[384] + wl[2]*hp[768] + wl[3]*hp[1152];
  }
  float v = fmaxf(0.25f*acc + b1[c], 0.f);
  hact[n*HID + c] = v;

  // fused alpha2 row-dots: asrc2[n,h] = sum_c v_c * wa_s2[c*4+h]
  float pr[8];
#pragma unroll
  for (int h = 0; h < 4; ++h){ pr[h] = v * wa_s2[c*4+h]; pr[4+h] = v * wa_d2[c*4+h]; }
#pragma unroll
  for (int o = 32; o > 0; o >>= 1){
#pragma unroll
    for (int q = 0; q < 8; ++q) pr[q] += __shfl_xor(pr[q], o, 64);
  }
  if (lane == 0){
#pragma unroll
    for (int q = 0; q < 8; ++q) red[w][q] = pr[q];
  }
  __syncthreads();
  if (t < 8){
    float s2 = 0.f;
#pragma unroll
    for (int ww = 0; ww < 6; ++ww) s2 += red[ww][t];
    if (t < 4) asrc2[n*4 + t] = s2; else adst2[n*4 + t - 4] = s2;
  }
}

// ---- layer-2 fused: softmax + agg in hact-space -> G[2000, H*384] ----------
__global__ __launch_bounds__(384) void k_gat2(const int* __restrict__ offsets,
                      const int* __restrict__ csr, const int* __restrict__ srcv,
                      const float* __restrict__ asrc, const float* __restrict__ adst,
                      float* eatt, const float* __restrict__ hact,
                      float* __restrict__ G){
  __shared__ float wts[DCAP][4];
  __shared__ int   ssrc[DCAP];
  __shared__ float wl[4];
  int n = blockIdx.x, t = threadIdx.x;
  int w = t >> 6, lane = t & 63;
  int lo = offsets[n], hi = offsets[n+1];
  int deg = hi - lo;
  bool big = deg > DCAP;
  if (w < 4) gat_softmax(n, lo, hi, w, lane, big, csr, srcv, asrc, adst, eatt, wts, ssrc, wl);
  __syncthreads();

  int c = t;
  float a0 = 0.f, a1 = 0.f, a2 = 0.f, a3 = 0.f;
  for (int j = 0; j < deg; ++j){
    int s; float w0, w1, w2, w3;
    if (big){ int e = csr[lo+j]; s = srcv[e];
      w0 = eatt[e*4+0]; w1 = eatt[e*4+1]; w2 = eatt[e*4+2]; w3 = eatt[e*4+3];
    } else { s = ssrc[j]; w0 = wts[j][0]; w1 = wts[j][1]; w2 = wts[j][2]; w3 = wts[j][3]; }
    float v = hact[(size_t)s*HID + c];
    a0 += w0*v; a1 += w1*v; a2 += w2*v; a3 += w3*v;
  }
  {
    float v = hact[(size_t)n*HID + c];
    a0 += wl[0]*v; a1 += wl[1]*v; a2 += wl[2]*v; a3 += wl[3]*v;
  }
  float* g = G + (size_t)n*1536 + c;
  g[0] = a0; g[384] = a1; g[768] = a2; g[1152] = a3;
}

// ---- split-K f32 GEMM: P[s] += G[2000,1536] @ W2v[1536,768] (K slice s) ----
#define FMA8(i, av) \
  acc[i][0]+=(av)*y0.x; acc[i][1]+=(av)*y0.y; acc[i][2]+=(av)*y0.z; acc[i][3]+=(av)*y0.w; \
  acc[i][4]+=(av)*y1.x; acc[i][5]+=(av)*y1.y; acc[i][6]+=(av)*y1.z; acc[i][7]+=(av)*y1.w;

__global__ __launch_bounds__(256) void k_gemm2(const float* __restrict__ A,
                                               const float* __restrict__ B,
                                               float* __restrict__ P){
  __shared__ float As[16][132];
  __shared__ float Bs[16][132];
  int t = threadIdx.x;
  int bn = blockIdx.x * 128;
  int bm = blockIdx.y * 128;
  int s  = blockIdx.z;
  int tm = t >> 4, tn = t & 15;
  float acc[8][8] = {};
  int arow = t >> 1;
  int ak   = (t & 1) * 8;
  int bk   = t >> 4;
  int bc   = (t & 15) * 4;
  int k0end = (s+1)*KSL;
  for (int k0 = s*KSL; k0 < k0end; k0 += 16){
    float4 a0 = make_float4(0,0,0,0), a1 = a0;
    int gm = bm + arow;
    if (gm < GM){
      a0 = *(const float4*)&A[(size_t)gm*GK + k0 + ak];
      a1 = *(const float4*)&A[(size_t)gm*GK + k0 + ak + 4];
    }
    float4 bv0 = *(const float4*)&B[(size_t)(k0+bk)*GN + bn + bc];
    float4 bv1 = *(const float4*)&B[(size_t)(k0+bk)*GN + bn + 64 + bc];
    __syncthreads();
    As[ak+0][arow] = a0.x; As[ak+1][arow] = a0.y; As[ak+2][arow] = a0.z; As[ak+3][arow] = a0.w;
    As[ak+4][arow] = a1.x; As[ak+5][arow] = a1.y; As[ak+6][arow] = a1.z; As[ak+7][arow] = a1.w;
    *(float4*)&Bs[bk][bc]      = bv0;
    *(float4*)&Bs[bk][64 + bc] = bv1;
    __syncthreads();
#pragma unroll
    for (int k = 0; k < 16; ++k){
      float4 x0 = *(const float4*)&As[k][tm*4];
      float4 x1 = *(const float4*)&As[k][64 + tm*4];
      float4 y0 = *(const float4*)&Bs[k][tn*4];
      float4 y1 = *(const float4*)&Bs[k][64 + tn*4];
      FMA8(0, x0.x) FMA8(1, x0.y) FMA8(2, x0.z) FMA8(3, x0.w)
      FMA8(4, x1.x) FMA8(5, x1.y) FMA8(6, x1.z) FMA8(7, x1.w)
    }
  }
  float* Pp = P + (size_t)s*GM*GN;
#pragma unroll
  for (int i = 0; i < 8; ++i){
    int r = bm + ((i < 4) ? (tm*4 + i) : (64 + tm*4 + (i-4)));
    if (r < GM){
      float4 v0; v0.x=acc[i][0]; v0.y=acc[i][1]; v0.z=acc[i][2]; v0.w=acc[i][3];
      float4 v1; v1.x=acc[i][4]; v1.y=acc[i][5]; v1.z=acc[i][6]; v1.w=acc[i][7];
      *(float4*)&Pp[(size_t)r*GN + bn + tn*4]      = v0;
      *(float4*)&Pp[(size_t)r*GN + bn + 64 + tn*4] = v1;
    }
  }
}

// ---- fixed-order split-K reduce + 0.25 head-mean + bias --------------------
__global__ void k_reduce(const float* __restrict__ P, const float* __restrict__ b2,
                         float* __restrict__ out){
  int f = blockIdx.x * blockDim.x + threadIdx.x;   // f4 index < 2000*192
  if (f >= GM*GN/4) return;
  const float4* P4 = (const float4*)P;
  float4 acc = P4[f];
#pragma unroll
  for (int s = 1; s < SPLITK; ++s){
    float4 v = P4[(size_t)s*(GM*GN/4) + f];
    acc.x += v.x; acc.y += v.y; acc.z += v.z; acc.w += v.w;
  }
  float4 b = ((const float4*)b2)[f % (GN/4)];
  float4 r; r.x = 0.25f*acc.x + b.x; r.y = 0.25f*acc.y + b.y;
  r.z = 0.25f*acc.z + b.z; r.w = 0.25f*acc.w + b.w;
  ((float4*)out)[f] = r;
}

// ---------------------------------------------------------------------------
extern "C" void kernel_launch(void* const* d_in, const int* in_sizes, int n_in,
                              void* d_out, int out_size, void* d_ws, size_t ws_size,
                              hipStream_t stream){
  const int*   x     = (const int*)d_in[0];
  const int*   ei    = (const int*)d_in[1];
  const int*   ea    = (const int*)d_in[2];
  const float* x_emb = (const float*)d_in[3];
  const float* e_emb = (const float*)d_in[4];
  const float* W1    = (const float*)d_in[5];
  const float* as1   = (const float*)d_in[6];
  const float* ad1   = (const float*)d_in[7];
  const float* We1   = (const float*)d_in[8];
  const float* ae1   = (const float*)d_in[9];
  const float* b1    = (const float*)d_in[10];
  const float* W2    = (const float*)d_in[11];
  const float* as2   = (const float*)d_in[12];
  const float* ad2   = (const float*)d_in[13];
  const float* We2   = (const float*)d_in[14];
  const float* ae2   = (const float*)d_in[15];
  const float* b2    = (const float*)d_in[16];
  const int* srcv = ei;
  const int* dstv = ei + NE;
  float* out = (float*)d_out;

  char* p = (char*)d_ws;
  auto take = [&](size_t n){ void* q = (void*)p; p += (n + 255) & ~(size_t)255; return q; };
  int*   counts  = (int*)take(NN*4);
  int*   offsets = (int*)take((NN+1)*4);
  int*   cursor  = (int*)take(NN*4);
  int*   csr     = (int*)take(NE*4);
  float* wa_s1   = (float*)take(EMBD*NH*4);
  float* wa_d1   = (float*)take(EMBD*NH*4);
  float* we_a1   = (float*)take(EMBD*NH*4);
  float* wa_s2   = (float*)take(HID*NH*4);
  float* wa_d2   = (float*)take(HID*NH*4);
  float* we_a2   = (float*)take(EMBD*NH*4);
  float* xa_s1   = (float*)take(178*NH*4);
  float* xa_d1   = (float*)take(178*NH*4);
  float* ew1     = (float*)take(18*NH*4);
  float* ew2     = (float*)take(18*NH*4);
  float* W2v     = (float*)take((size_t)GK*GN*4);        // 4.72 MB
  float* G       = (float*)take((size_t)NN*NH*HID*4);    // 12.29 MB
  // ---- aliased span: everything below is dead by the time k_gemm2 runs ----
  char*  bspan   = p;
  float* xh1     = (float*)take((size_t)178*NH*HID*4);
  float* hx1     = (float*)take((size_t)NN*NH*HID*4);
  float* eatt1   = (float*)take((size_t)NE*NH*4);
  float* eatt2   = (float*)take((size_t)NE*NH*4);
  float* hact    = (float*)take((size_t)NN*HID*4);
  float* asrc1   = (float*)take(NN*NH*4);
  float* adst1   = (float*)take(NN*NH*4);
  float* asrc2   = (float*)take(NN*NH*4);
  float* adst2   = (float*)take(NN*NH*4);
  // parts buffer overlaps the span above (written only after k_gat2 is done)
  float* parts   = (float*)bspan;
  {
    char* pend = bspan + ((size_t)SPLITK*GM*GN*4 + 255 & ~(size_t)255);
    if (pend > p) p = pend;
  }

  // CSR (deterministic after in-bucket sort)
  hipMemsetAsync(counts, 0, NN*4, stream);
  k_count<<<(NE+255)/256, 256, 0, stream>>>(dstv, counts);
  k_scan<<<1, 1024, 0, stream>>>(counts, offsets, cursor);
  k_fill<<<(NE+255)/256, 256, 0, stream>>>(dstv, cursor, csr);
  k_sort<<<(NN+255)/256, 256, 0, stream>>>(offsets, csr);

  // prep: collapses + W2v, then table dots
  k_prep1<<<15360 + 4608, 64, 0, stream>>>(W1, as1, ad1, We1, ae1, W2, as2, ad2,
                                           We2, ae2, wa_s1, wa_d1, we_a1, wa_s2,
                                           wa_d2, we_a2, W2v);
  k_prep2<<<1568, 64, 0, stream>>>(x_emb, e_emb, wa_s1, wa_d1, we_a1, we_a2,
                                   xa_s1, xa_d1, ew1, ew2);

  // xh1 = x_emb @ W1  [178,1536]
  { dim3 g(24, 3); k_gemm<<<g, 256, 0, stream>>>(x_emb, W1, xh1, 178, NH*HID, EMBD); }

  // hx1 gather + node/edge alpha terms
  k_misc<<<(NN*384 + NN*NH + NE*NH + 255)/256, 256, 0, stream>>>(
      x, ea, xh1, xa_s1, xa_d1, ew1, ew2, hx1, asrc1, adst1, eatt1, eatt2);

  // layer 1 fused -> hact, asrc2, adst2
  k_gat1<<<NN, 384, 0, stream>>>(offsets, csr, srcv, asrc1, adst1, eatt1, hx1,
                                 b1, wa_s2, wa_d2, hact, asrc2, adst2);

  // layer 2 fused agg-first -> G
  k_gat2<<<NN, 384, 0, stream>>>(offsets, csr, srcv, asrc2, adst2, eatt2, hact, G);

  // out = 0.25 * (G @ W2v) + b2   (split-K + deterministic reduce)
  { dim3 g(GN/128, 16, SPLITK); k_gemm2<<<g, 256, 0, stream>>>(G, W2v, parts); }
  k_reduce<<<(GM*GN/4 + 255)/256, 256, 0, stream>>>(parts, b2, out);
}

// Round 3
// 267.152 us; speedup vs baseline: 1.6539x; 1.1336x over previous
//
#include <hip/hip_runtime.h>
#include <hip/hip_bf16.h>

#define NN   2000
#define NE   32000
#define EMBD 768
#define NH   4
#define HID  384
#define FTD  768
#define NEG  0.2f
#define DCAP 1024

#define GM 2000
#define GN 768
#define GK 1536

typedef __bf16 bf16x8 __attribute__((ext_vector_type(8)));
typedef float  f32x4  __attribute__((ext_vector_type(4)));

__device__ inline float wsum(float v){
#pragma unroll
  for (int o = 32; o > 0; o >>= 1) v += __shfl_xor(v, o, 64);
  return v;
}
__device__ inline float wmax(float v){
#pragma unroll
  for (int o = 32; o > 0; o >>= 1) v = fmaxf(v, __shfl_xor(v, o, 64));
  return v;
}

// bf16 round-to-nearest-even split helpers
__device__ inline unsigned short f2bf(float f){
  unsigned u = __float_as_uint(f);
  unsigned r = (u + 0x7FFFu + ((u >> 16) & 1u)) >> 16;
  return (unsigned short)r;
}
__device__ inline float bf2f(unsigned short h){
  return __uint_as_float(((unsigned)h) << 16);
}

// ---- CSR build -------------------------------------------------------------
__global__ void k_count(const int* __restrict__ dst, int* __restrict__ counts){
  int e = blockIdx.x * blockDim.x + threadIdx.x;
  if (e < NE) atomicAdd(&counts[dst[e]], 1);
}

__global__ void k_scan(const int* __restrict__ counts, int* __restrict__ offsets,
                       int* __restrict__ cursor){
  __shared__ int s[1024];
  int t = threadIdx.x;
  int a = (2*t   < NN) ? counts[2*t  ] : 0;
  int b = (2*t+1 < NN) ? counts[2*t+1] : 0;
  s[t] = a + b;
  __syncthreads();
  for (int off = 1; off < 1024; off <<= 1){
    int v = (t >= off) ? s[t-off] : 0;
    __syncthreads();
    s[t] += v;
    __syncthreads();
  }
  int base = (t > 0) ? s[t-1] : 0;
  if (2*t < NN){ offsets[2*t] = base; cursor[2*t] = base; }
  if (2*t+1 < NN){ offsets[2*t+1] = base + a; cursor[2*t+1] = base + a; }
  if (2*t == NN) offsets[NN] = base;
}

__global__ void k_fill(const int* __restrict__ dst, int* __restrict__ cursor,
                       int* __restrict__ csr){
  int e = blockIdx.x * blockDim.x + threadIdx.x;
  if (e < NE){
    int p = atomicAdd(&cursor[dst[e]], 1);
    csr[p] = e;
  }
}

__global__ void k_sort(const int* __restrict__ offsets, int* __restrict__ csr){
  int n = blockIdx.x * blockDim.x + threadIdx.x;
  if (n >= NN) return;
  int lo = offsets[n], hi = offsets[n+1];
  for (int i = lo+1; i < hi; ++i){
    int v = csr[i], j = i-1;
    while (j >= lo && csr[j] > v){ csr[j+1] = csr[j]; --j; }
    csr[j+1] = v;
  }
}

// ---- prep 1: weight collapses (64-thread blocks) ---------------------------
__global__ void k_prep1(const float* __restrict__ W1,  const float* __restrict__ as1,
                        const float* __restrict__ ad1, const float* __restrict__ We1,
                        const float* __restrict__ ae1, const float* __restrict__ W2,
                        const float* __restrict__ as2, const float* __restrict__ ad2,
                        const float* __restrict__ We2, const float* __restrict__ ae2,
                        float* __restrict__ wa_s1, float* __restrict__ wa_d1,
                        float* __restrict__ we_a1, float* __restrict__ wa_s2,
                        float* __restrict__ wa_d2, float* __restrict__ we_a2){
  int b = blockIdx.x, lane = threadIdx.x;
  const float *W, *a; float* o; int C;
  if (b < 3072)       {          W=W1;  a=as1; o=wa_s1; C=384; }
  else if (b < 6144)  { b-=3072; W=W1;  a=ad1; o=wa_d1; C=384; }
  else if (b < 9216)  { b-=6144; W=We1; a=ae1; o=we_a1; C=384; }
  else if (b < 10752) { b-=9216; W=W2;  a=as2; o=wa_s2; C=768; }
  else if (b < 12288) { b-=10752;W=W2;  a=ad2; o=wa_d2; C=768; }
  else                { b-=12288;W=We2; a=ae2; o=we_a2; C=768; }
  int k = b >> 2, h = b & 3;
  const float* wr = W + (size_t)k * (4*C) + (size_t)h * C;
  const float* ar = a + (size_t)h * C;
  float acc = 0.f;
  for (int c = lane; c < C; c += 64) acc += wr[c] * ar[c];
  acc = wsum(acc);
  if (lane == 0) o[k*NH + h] = acc;
}

// ---- prep: W2 -> B^T bf16 hi/lo.  Bt[c][h*384+k'] = W2[k'][h*768+c] --------
__global__ __launch_bounds__(256) void k_bt(const float* __restrict__ W2,
                                            unsigned short* __restrict__ Bh,
                                            unsigned short* __restrict__ Bl){
  __shared__ float tile[64][65];
  int bk = blockIdx.x * 64;   // k in [0,1536)
  int bc = blockIdx.y * 64;   // c in [0,768)
  int t = threadIdx.x;
  int cc = t & 63, kk4 = t >> 6;
#pragma unroll
  for (int i = 0; i < 16; ++i){
    int kk = kk4*16 + i;
    int k = bk + kk;
    int h = k / 384, kp = k - h*384;
    tile[kk][cc] = W2[(size_t)kp*3072 + h*768 + bc + cc];
  }
  __syncthreads();
  int kk2 = t & 63, cc4 = t >> 6;
#pragma unroll
  for (int i = 0; i < 16; ++i){
    int c2 = cc4*16 + i;
    float v = tile[kk2][c2];
    unsigned short hi = f2bf(v);
    unsigned short lo = f2bf(v - bf2f(hi));
    size_t o = (size_t)(bc + c2)*GK + bk + kk2;
    Bh[o] = hi; Bl[o] = lo;
  }
}

// ---- prep 2: table row-dots ------------------------------------------------
__global__ void k_prep2(const float* __restrict__ x_emb, const float* __restrict__ e_emb,
                        const float* __restrict__ wa_s1, const float* __restrict__ wa_d1,
                        const float* __restrict__ we_a1, const float* __restrict__ we_a2,
                        float* __restrict__ xa_s1, float* __restrict__ xa_d1,
                        float* __restrict__ ew1, float* __restrict__ ew2){
  int b = blockIdx.x, lane = threadIdx.x;
  const float *A, *wv; float* o;
  if (b < 712)        {          A=x_emb; wv=wa_s1; o=xa_s1; }
  else if (b < 1424)  { b-=712;  A=x_emb; wv=wa_d1; o=xa_d1; }
  else if (b < 1496)  { b-=1424; A=e_emb; wv=we_a1; o=ew1; }
  else                { b-=1496; A=e_emb; wv=we_a2; o=ew2; }
  int r = b >> 2, h = b & 3;
  const float* ar = A + (size_t)r * EMBD;
  float acc = 0.f;
  for (int k = lane; k < EMBD; k += 64) acc += ar[k] * wv[k*NH + h];
  acc = wsum(acc);
  if (lane == 0) o[r*NH + h] = acc;
}

// ---- xh1 = x_emb @ W1 [178,1536], 32x64 tiles, split-K=2 -------------------
__global__ __launch_bounds__(256) void k_gemm1(const float* __restrict__ A,
                                               const float* __restrict__ B,
                                               float* __restrict__ P){
  __shared__ float As[16][34];
  __shared__ float Bs[16][68];
  int t = threadIdx.x;
  int bn = blockIdx.x * 64;
  int bm = blockIdx.y * 32;
  int s  = blockIdx.z;
  float acc[2][4] = {};
  int tm = t >> 4, tn = t & 15;
  int ar = t >> 3, ac = (t & 7) * 2;
  int br = t >> 4, bc = (t & 15) * 4;
  int kend = s*384 + 384;
  for (int k0 = s*384; k0 < kend; k0 += 16){
    float a0 = 0.f, a1 = 0.f;
    if (bm + ar < 178){
      const float* ap = &A[(size_t)(bm+ar)*EMBD + k0 + ac];
      a0 = ap[0]; a1 = ap[1];
    }
    As[ac][ar] = a0; As[ac+1][ar] = a1;
    *(float4*)&Bs[br][bc] = *(const float4*)&B[(size_t)(k0+br)*1536 + bn + bc];
    __syncthreads();
#pragma unroll
    for (int k = 0; k < 16; ++k){
      float x0 = As[k][tm*2], x1 = As[k][tm*2+1];
      float4 b4 = *(const float4*)&Bs[k][tn*4];
      acc[0][0] += x0*b4.x; acc[0][1] += x0*b4.y; acc[0][2] += x0*b4.z; acc[0][3] += x0*b4.w;
      acc[1][0] += x1*b4.x; acc[1][1] += x1*b4.y; acc[1][2] += x1*b4.z; acc[1][3] += x1*b4.w;
    }
    __syncthreads();
  }
#pragma unroll
  for (int i = 0; i < 2; ++i){
    int r = bm + tm*2 + i;
    if (r < 178){
      float4 v; v.x=acc[i][0]; v.y=acc[i][1]; v.z=acc[i][2]; v.w=acc[i][3];
      *(float4*)&P[(size_t)s*178*1536 + (size_t)r*1536 + bn + tn*4] = v;
    }
  }
}

// ---- misc fused: xh1 reduce + node alpha + edge alpha + edge src pairs -----
#define S0 (178*1536/4)
#define S1 (NN*NH)
#define S2 (NE*NH)
#define S3 (NE)
__global__ void k_misc(const int* __restrict__ x, const int* __restrict__ ea,
                       const int* __restrict__ srcv,
                       const float* __restrict__ P, float* __restrict__ xh1,
                       const float* __restrict__ xa_s1, const float* __restrict__ xa_d1,
                       const float* __restrict__ ew1, const float* __restrict__ ew2,
                       float* __restrict__ asrc1, float* __restrict__ adst1,
                       float* __restrict__ eatt1, float* __restrict__ eatt2,
                       int* __restrict__ sa, int* __restrict__ sb){
  int i = blockIdx.x * blockDim.x + threadIdx.x;
  if (i < S0){
    float4 u = ((const float4*)P)[i];
    float4 v = ((const float4*)P)[S0 + i];
    float4 r; r.x=u.x+v.x; r.y=u.y+v.y; r.z=u.z+v.z; r.w=u.w+v.w;
    ((float4*)xh1)[i] = r;
  } else if (i < S0 + S1){
    int i2 = i - S0;
    int n = i2 >> 2, h = i2 & 3;
    int a = x[2*n], b = x[2*n+1];
    asrc1[i2] = xa_s1[a*NH+h] + xa_s1[b*NH+h];
    adst1[i2] = xa_d1[a*NH+h] + xa_d1[b*NH+h];
  } else if (i < S0 + S1 + S2){
    int i2 = i - S0 - S1;
    int e = i2 >> 2, h = i2 & 3;
    int a = ea[2*e], b = ea[2*e+1];
    eatt1[i2] = ew1[a*NH+h] + ew1[b*NH+h];
    eatt2[i2] = ew2[a*NH+h] + ew2[b*NH+h];
  } else if (i < S0 + S1 + S2 + S3){
    int e = i - S0 - S1 - S2;
    int s = srcv[e];
    sa[e] = x[2*s]; sb[e] = x[2*s+1];
  }
}

// ---- fused softmax (wave-per-head) -----------------------------------------
__device__ void gat_softmax(int n, int lo, int hi, int w, int lane, bool big,
                            const int* __restrict__ csr, const int* __restrict__ srcv,
                            const int* __restrict__ sa, const int* __restrict__ sb,
                            const float* __restrict__ asrc, const float* __restrict__ adst,
                            float* eatt, float (*wts)[4], int* sA, int* sB, float* wl){
  int deg = hi - lo;
  float ad_n = adst[n*NH + w];
  float as_n = asrc[n*NH + w];
  float mx = -3.4e38f, sae = 0.f;
  if (!big){
    for (int p = lo + lane; p < hi; p += 64){
      int e = csr[p]; int s = srcv[e];
      if (w == 0){ if (sA){ sA[p - lo] = sa[e]; sB[p - lo] = sb[e]; } }
      float ae = eatt[e*NH + w];
      float al = asrc[s*NH + w] + ad_n + ae;
      al = (al > 0.f) ? al : NEG * al;
      wts[p - lo][w] = al;
      sae += ae; mx = fmaxf(mx, al);
    }
    mx = wmax(mx); sae = wsum(sae);
    float all_ = as_n + ad_n + sae / fmaxf((float)deg, 1.f);
    all_ = (all_ > 0.f) ? all_ : NEG * all_;
    mx = fmaxf(mx, all_);
    float den = 0.f;
    for (int p = lo + lane; p < hi; p += 64){
      float xx = expf(wts[p - lo][w] - mx);
      wts[p - lo][w] = xx; den += xx;
    }
    den = wsum(den);
    float exl = expf(all_ - mx);
    den += exl;
    float inv = 1.f / den;
    for (int p = lo + lane; p < hi; p += 64) wts[p - lo][w] *= inv;
    if (lane == 0) wl[w] = exl * inv;
  } else {
    for (int p = lo + lane; p < hi; p += 64){
      int e = csr[p];
      float ae = eatt[e*NH + w];
      float al = asrc[srcv[e]*NH + w] + ad_n + ae;
      al = (al > 0.f) ? al : NEG * al;
      eatt[e*NH + w] = al;
      sae += ae; mx = fmaxf(mx, al);
    }
    mx = wmax(mx); sae = wsum(sae);
    float all_ = as_n + ad_n + sae / fmaxf((float)deg, 1.f);
    all_ = (all_ > 0.f) ? all_ : NEG * all_;
    mx = fmaxf(mx, all_);
    float den = 0.f;
    for (int p = lo + lane; p < hi; p += 64){
      int e = csr[p];
      float xx = expf(eatt[e*NH + w] - mx);
      eatt[e*NH + w] = xx; den += xx;
    }
    den = wsum(den);
    float exl = expf(all_ - mx);
    den += exl;
    float inv = 1.f / den;
    for (int p = lo + lane; p < hi; p += 64) eatt[csr[p]*NH + w] *= inv;
    if (lane == 0) wl[w] = exl * inv;
  }
}

// ---- layer-1 fused: softmax + agg from the hot xh1 table + alpha2 dots -----
__global__ __launch_bounds__(384) void k_gat1(const int* __restrict__ offsets,
                      const int* __restrict__ csr, const int* __restrict__ srcv,
                      const int* __restrict__ sa, const int* __restrict__ sb,
                      const int* __restrict__ x,
                      const float* __restrict__ asrc, const float* __restrict__ adst,
                      float* eatt, const float* __restrict__ xh1,
                      const float* __restrict__ b1, const float* __restrict__ wa_s2,
                      const float* __restrict__ wa_d2, float* __restrict__ hact,
                      float* __restrict__ asrc2, float* __restrict__ adst2){
  __shared__ float wts[DCAP][4];
  __shared__ int   sA[DCAP], sB[DCAP];
  __shared__ float wl[4];
  __shared__ float red[6][8];
  int n = blockIdx.x, t = threadIdx.x;
  int w = t >> 6, lane = t & 63;
  int lo = offsets[n], hi = offsets[n+1];
  int deg = hi - lo;
  bool big = deg > DCAP;
  if (w < 4) gat_softmax(n, lo, hi, w, lane, big, csr, srcv, sa, sb, asrc, adst,
                         eatt, wts, sA, sB, wl);
  __syncthreads();

  int c = t;  // 0..383
  float acc = 0.f;
  for (int j = 0; j < deg; ++j){
    int a, b; float w0, w1, w2, w3;
    if (big){ int e = csr[lo+j]; a = sa[e]; b = sb[e];
      w0 = eatt[e*4+0]; w1 = eatt[e*4+1]; w2 = eatt[e*4+2]; w3 = eatt[e*4+3];
    } else { a = sA[j]; b = sB[j];
      w0 = wts[j][0]; w1 = wts[j][1]; w2 = wts[j][2]; w3 = wts[j][3]; }
    const float* pa = xh1 + (size_t)a*1536 + c;
    const float* pb = xh1 + (size_t)b*1536 + c;
    acc += w0*(pa[0]+pb[0]) + w1*(pa[384]+pb[384])
         + w2*(pa[768]+pb[768]) + w3*(pa[1152]+pb[1152]);
  }
  {
    int a = x[2*n], b = x[2*n+1];
    const float* pa = xh1 + (size_t)a*1536 + c;
    const float* pb = xh1 + (size_t)b*1536 + c;
    acc += wl[0]*(pa[0]+pb[0]) + wl[1]*(pa[384]+pb[384])
         + wl[2]*(pa[768]+pb[768]) + wl[3]*(pa[1152]+pb[1152]);
  }
  float v = fmaxf(0.25f*acc + b1[c], 0.f);
  hact[n*HID + c] = v;

  float pr[8];
#pragma unroll
  for (int h = 0; h < 4; ++h){ pr[h] = v * wa_s2[c*4+h]; pr[4+h] = v * wa_d2[c*4+h]; }
#pragma unroll
  for (int o = 32; o > 0; o >>= 1){
#pragma unroll
    for (int q = 0; q < 8; ++q) pr[q] += __shfl_xor(pr[q], o, 64);
  }
  if (lane == 0){
#pragma unroll
    for (int q = 0; q < 8; ++q) red[w][q] = pr[q];
  }
  __syncthreads();
  if (t < 8){
    float s2 = 0.f;
#pragma unroll
    for (int ww = 0; ww < 6; ++ww) s2 += red[ww][t];
    if (t < 4) asrc2[n*4 + t] = s2; else adst2[n*4 + t - 4] = s2;
  }
}

// ---- layer-2 fused: softmax + agg -> G as bf16 hi/lo -----------------------
__global__ __launch_bounds__(384) void k_gat2(const int* __restrict__ offsets,
                      const int* __restrict__ csr, const int* __restrict__ srcv,
                      const float* __restrict__ asrc, const float* __restrict__ adst,
                      float* eatt, const float* __restrict__ hact,
                      unsigned short* __restrict__ Gh, unsigned short* __restrict__ Gl){
  __shared__ float wts[DCAP][4];
  __shared__ int   ssrc[DCAP];
  __shared__ float wl[4];
  int n = blockIdx.x, t = threadIdx.x;
  int w = t >> 6, lane = t & 63;
  int lo = offsets[n], hi = offsets[n+1];
  int deg = hi - lo;
  bool big = deg > DCAP;
  // stage src indices via sA=ssrc (sa array here holds srcv directly)
  if (w < 4){
    int d2 = hi - lo;
    float ad_n = adst[n*NH + w];
    float as_n = asrc[n*NH + w];
    float mx = -3.4e38f, sae = 0.f;
    if (!big){
      for (int p = lo + lane; p < hi; p += 64){
        int e = csr[p]; int s = srcv[e];
        if (w == 0) ssrc[p - lo] = s;
        float ae = eatt[e*NH + w];
        float al = asrc[s*NH + w] + ad_n + ae;
        al = (al > 0.f) ? al : NEG * al;
        wts[p - lo][w] = al;
        sae += ae; mx = fmaxf(mx, al);
      }
      mx = wmax(mx); sae = wsum(sae);
      float all_ = as_n + ad_n + sae / fmaxf((float)d2, 1.f);
      all_ = (all_ > 0.f) ? all_ : NEG * all_;
      mx = fmaxf(mx, all_);
      float den = 0.f;
      for (int p = lo + lane; p < hi; p += 64){
        float xx = expf(wts[p - lo][w] - mx);
        wts[p - lo][w] = xx; den += xx;
      }
      den = wsum(den);
      float exl = expf(all_ - mx);
      den += exl;
      float inv = 1.f / den;
      for (int p = lo + lane; p < hi; p += 64) wts[p - lo][w] *= inv;
      if (lane == 0) wl[w] = exl * inv;
    } else {
      gat_softmax(n, lo, hi, w, lane, true, csr, srcv, nullptr, nullptr,
                  asrc, adst, eatt, wts, nullptr, nullptr, wl);
    }
  }
  __syncthreads();

  int c = t;
  float a0 = 0.f, a1 = 0.f, a2 = 0.f, a3 = 0.f;
  for (int j = 0; j < deg; ++j){
    int s; float w0, w1, w2, w3;
    if (big){ int e = csr[lo+j]; s = srcv[e];
      w0 = eatt[e*4+0]; w1 = eatt[e*4+1]; w2 = eatt[e*4+2]; w3 = eatt[e*4+3];
    } else { s = ssrc[j]; w0 = wts[j][0]; w1 = wts[j][1]; w2 = wts[j][2]; w3 = wts[j][3]; }
    float v = hact[(size_t)s*HID + c];
    a0 += w0*v; a1 += w1*v; a2 += w2*v; a3 += w3*v;
  }
  {
    float v = hact[(size_t)n*HID + c];
    a0 += wl[0]*v; a1 += wl[1]*v; a2 += wl[2]*v; a3 += wl[3]*v;
  }
  size_t base = (size_t)n*GK + c;
  float vv[4] = {a0, a1, a2, a3};
#pragma unroll
  for (int h = 0; h < 4; ++h){
    unsigned short hi16 = f2bf(vv[h]);
    unsigned short lo16 = f2bf(vv[h] - bf2f(hi16));
    Gh[base + h*384] = hi16;
    Gl[base + h*384] = lo16;
  }
}

// ---- layer-2 MFMA GEMM: out = 0.25*(G @ Bt^T) + b2  (bf16 3-product) -------
// tile 128(M) x 64(N), 4 waves (2x2), wave tile 64x32, grid 192 XCD-swizzled
__global__ __launch_bounds__(256) void k_mm2(const unsigned short* __restrict__ Gh,
                                             const unsigned short* __restrict__ Gl,
                                             const unsigned short* __restrict__ Bh,
                                             const unsigned short* __restrict__ Bl,
                                             const float* __restrict__ b2,
                                             float* __restrict__ out){
  int b = blockIdx.x;
  int slot = (b & 7) * 24 + (b >> 3);       // cluster bn per XCD
  int bn = slot >> 4, bm = slot & 15;
  int wave = threadIdx.x >> 6, lane = threadIdx.x & 63;
  int wm = wave >> 1, wn = wave & 1;
  int r0 = bm*128 + wm*64;
  int c0 = bn*64 + wn*32;
  int rl = lane & 15;
  int kg = (lane >> 4) * 8;

  const unsigned short* pAh[4];
  const unsigned short* pAl[4];
#pragma unroll
  for (int i = 0; i < 4; ++i){
    int row = r0 + i*16 + rl;
    row = (row < GM) ? row : (GM-1);
    size_t o = (size_t)row*GK + kg;
    pAh[i] = Gh + o; pAl[i] = Gl + o;
  }
  const unsigned short* pBh[2];
  const unsigned short* pBl[2];
#pragma unroll
  for (int j = 0; j < 2; ++j){
    size_t o = (size_t)(c0 + j*16 + rl)*GK + kg;
    pBh[j] = Bh + o; pBl[j] = Bl + o;
  }

  f32x4 acc[4][2] = {};
  for (int k0 = 0; k0 < GK; k0 += 32){
    bf16x8 ah[4], al[4], bh[2], bl[2];
#pragma unroll
    for (int i = 0; i < 4; ++i){
      ah[i] = *(const bf16x8*)(pAh[i] + k0);
      al[i] = *(const bf16x8*)(pAl[i] + k0);
    }
#pragma unroll
    for (int j = 0; j < 2; ++j){
      bh[j] = *(const bf16x8*)(pBh[j] + k0);
      bl[j] = *(const bf16x8*)(pBl[j] + k0);
    }
#pragma unroll
    for (int i = 0; i < 4; ++i){
#pragma unroll
      for (int j = 0; j < 2; ++j){
        acc[i][j] = __builtin_amdgcn_mfma_f32_16x16x32_bf16(ah[i], bh[j], acc[i][j], 0, 0, 0);
        acc[i][j] = __builtin_amdgcn_mfma_f32_16x16x32_bf16(ah[i], bl[j], acc[i][j], 0, 0, 0);
        acc[i][j] = __builtin_amdgcn_mfma_f32_16x16x32_bf16(al[i], bh[j], acc[i][j], 0, 0, 0);
      }
    }
  }

#pragma unroll
  for (int i = 0; i < 4; ++i){
#pragma unroll
    for (int j = 0; j < 2; ++j){
      int col = c0 + j*16 + rl;
      float bb = b2[col];
#pragma unroll
      for (int r = 0; r < 4; ++r){
        int row = r0 + i*16 + (lane >> 4)*4 + r;
        if (row < GM) out[(size_t)row*GN + col] = 0.25f*acc[i][j][r] + bb;
      }
    }
  }
}

// ---------------------------------------------------------------------------
extern "C" void kernel_launch(void* const* d_in, const int* in_sizes, int n_in,
                              void* d_out, int out_size, void* d_ws, size_t ws_size,
                              hipStream_t stream){
  const int*   x     = (const int*)d_in[0];
  const int*   ei    = (const int*)d_in[1];
  const int*   ea    = (const int*)d_in[2];
  const float* x_emb = (const float*)d_in[3];
  const float* e_emb = (const float*)d_in[4];
  const float* W1    = (const float*)d_in[5];
  const float* as1   = (const float*)d_in[6];
  const float* ad1   = (const float*)d_in[7];
  const float* We1   = (const float*)d_in[8];
  const float* ae1   = (const float*)d_in[9];
  const float* b1    = (const float*)d_in[10];
  const float* W2    = (const float*)d_in[11];
  const float* as2   = (const float*)d_in[12];
  const float* ad2   = (const float*)d_in[13];
  const float* We2   = (const float*)d_in[14];
  const float* ae2   = (const float*)d_in[15];
  const float* b2    = (const float*)d_in[16];
  const int* srcv = ei;
  const int* dstv = ei + NE;
  float* out = (float*)d_out;

  char* p = (char*)d_ws;
  auto take = [&](size_t n){ void* q = (void*)p; p += (n + 255) & ~(size_t)255; return q; };
  int*   counts  = (int*)take(NN*4);
  int*   offsets = (int*)take((NN+1)*4);
  int*   cursor  = (int*)take(NN*4);
  int*   csr     = (int*)take(NE*4);
  float* wa_s1   = (float*)take(EMBD*NH*4);
  float* wa_d1   = (float*)take(EMBD*NH*4);
  float* we_a1   = (float*)take(EMBD*NH*4);
  float* wa_s2   = (float*)take(HID*NH*4);
  float* wa_d2   = (float*)take(HID*NH*4);
  float* we_a2   = (float*)take(EMBD*NH*4);
  float* xa_s1   = (float*)take(178*NH*4);
  float* xa_d1   = (float*)take(178*NH*4);
  float* ew1     = (float*)take(18*NH*4);
  float* ew2     = (float*)take(18*NH*4);
  float* xh1     = (float*)take((size_t)178*1536*4);
  float* parts1  = (float*)take((size_t)2*178*1536*4);
  unsigned short* Bth = (unsigned short*)take((size_t)GN*GK*2);
  unsigned short* Btl = (unsigned short*)take((size_t)GN*GK*2);
  unsigned short* Gh  = (unsigned short*)take((size_t)GM*GK*2);
  unsigned short* Gl  = (unsigned short*)take((size_t)GM*GK*2);
  int*   sa      = (int*)take(NE*4);
  int*   sb      = (int*)take(NE*4);
  float* eatt1   = (float*)take((size_t)NE*NH*4);
  float* eatt2   = (float*)take((size_t)NE*NH*4);
  float* hact    = (float*)take((size_t)NN*HID*4);
  float* asrc1   = (float*)take(NN*NH*4);
  float* adst1   = (float*)take(NN*NH*4);
  float* asrc2   = (float*)take(NN*NH*4);
  float* adst2   = (float*)take(NN*NH*4);

  // CSR (deterministic after in-bucket sort)
  hipMemsetAsync(counts, 0, NN*4, stream);
  k_count<<<(NE+255)/256, 256, 0, stream>>>(dstv, counts);
  k_scan<<<1, 1024, 0, stream>>>(counts, offsets, cursor);
  k_fill<<<(NE+255)/256, 256, 0, stream>>>(dstv, cursor, csr);
  k_sort<<<(NN+255)/256, 256, 0, stream>>>(offsets, csr);

  // prep
  k_prep1<<<15360, 64, 0, stream>>>(W1, as1, ad1, We1, ae1, W2, as2, ad2,
                                    We2, ae2, wa_s1, wa_d1, we_a1, wa_s2,
                                    wa_d2, we_a2);
  { dim3 g(GK/64, GN/64); k_bt<<<g, 256, 0, stream>>>(W2, Bth, Btl); }
  k_prep2<<<1568, 64, 0, stream>>>(x_emb, e_emb, wa_s1, wa_d1, we_a1, we_a2,
                                   xa_s1, xa_d1, ew1, ew2);

  // xh1 = x_emb @ W1 (split-K=2)
  { dim3 g(24, 6, 2); k_gemm1<<<g, 256, 0, stream>>>(x_emb, W1, parts1); }

  // fused elementwise (xh1 reduce, alpha terms, src pairs)
  k_misc<<<(S0+S1+S2+S3 + 255)/256, 256, 0, stream>>>(
      x, ea, srcv, parts1, xh1, xa_s1, xa_d1, ew1, ew2,
      asrc1, adst1, eatt1, eatt2, sa, sb);

  // layer 1 fused -> hact, asrc2, adst2
  k_gat1<<<NN, 384, 0, stream>>>(offsets, csr, srcv, sa, sb, x, asrc1, adst1,
                                 eatt1, xh1, b1, wa_s2, wa_d2, hact, asrc2, adst2);

  // layer 2 fused agg-first -> G (bf16 hi/lo)
  k_gat2<<<NN, 384, 0, stream>>>(offsets, csr, srcv, asrc2, adst2, eatt2, hact, Gh, Gl);

  // out = 0.25*(G @ Bt^T) + b2 via bf16 3-product MFMA
  k_mm2<<<192, 256, 0, stream>>>(Gh, Gl, Bth, Btl, b2, out);
}

// Round 4
// 207.904 us; speedup vs baseline: 2.1252x; 1.2850x over previous
//
#include <hip/hip_runtime.h>
#include <hip/hip_bf16.h>

#define NN   2000
#define NE   32000
#define EMBD 768
#define NH   4
#define HID  384
#define FTD  768
#define NEG  0.2f
#define DCAP 1024

#define GM 2000
#define GN 768
#define GK 1536

typedef __bf16 bf16x8 __attribute__((ext_vector_type(8)));
typedef float  f32x4  __attribute__((ext_vector_type(4)));

__device__ inline float wsum(float v){
#pragma unroll
  for (int o = 32; o > 0; o >>= 1) v += __shfl_xor(v, o, 64);
  return v;
}
__device__ inline float wmax(float v){
#pragma unroll
  for (int o = 32; o > 0; o >>= 1) v = fmaxf(v, __shfl_xor(v, o, 64));
  return v;
}

// bf16 round-to-nearest-even split helpers
__device__ inline unsigned short f2bf(float f){
  unsigned u = __float_as_uint(f);
  unsigned r = (u + 0x7FFFu + ((u >> 16) & 1u)) >> 16;
  return (unsigned short)r;
}
__device__ inline float bf2f(unsigned short h){
  return __uint_as_float(((unsigned)h) << 16);
}

__device__ inline void gload16(const void* g, void* l){
  __builtin_amdgcn_global_load_lds((const __attribute__((address_space(1))) void*)g,
                                   (__attribute__((address_space(3))) void*)l, 16, 0, 0);
}

// ---- CSR build -------------------------------------------------------------
__global__ void k_count(const int* __restrict__ dst, int* __restrict__ counts){
  int e = blockIdx.x * blockDim.x + threadIdx.x;
  if (e < NE) atomicAdd(&counts[dst[e]], 1);
}

__global__ void k_scan(const int* __restrict__ counts, int* __restrict__ offsets,
                       int* __restrict__ cursor){
  __shared__ int s[1024];
  int t = threadIdx.x;
  int a = (2*t   < NN) ? counts[2*t  ] : 0;
  int b = (2*t+1 < NN) ? counts[2*t+1] : 0;
  s[t] = a + b;
  __syncthreads();
  for (int off = 1; off < 1024; off <<= 1){
    int v = (t >= off) ? s[t-off] : 0;
    __syncthreads();
    s[t] += v;
    __syncthreads();
  }
  int base = (t > 0) ? s[t-1] : 0;
  if (2*t < NN){ offsets[2*t] = base; cursor[2*t] = base; }
  if (2*t+1 < NN){ offsets[2*t+1] = base + a; cursor[2*t+1] = base + a; }
  if (2*t == NN) offsets[NN] = base;
}

__global__ void k_fill(const int* __restrict__ dst, int* __restrict__ cursor,
                       int* __restrict__ csr){
  int e = blockIdx.x * blockDim.x + threadIdx.x;
  if (e < NE){
    int p = atomicAdd(&cursor[dst[e]], 1);
    csr[p] = e;
  }
}

__global__ void k_sort(const int* __restrict__ offsets, int* __restrict__ csr){
  int n = blockIdx.x * blockDim.x + threadIdx.x;
  if (n >= NN) return;
  int lo = offsets[n], hi = offsets[n+1];
  for (int i = lo+1; i < hi; ++i){
    int v = csr[i], j = i-1;
    while (j >= lo && csr[j] > v){ csr[j+1] = csr[j]; --j; }
    csr[j+1] = v;
  }
}

// ---- prep 1: weight collapses, paired (read W once, dot 2 vectors) ---------
__global__ void k_prep1(const float* __restrict__ W1,  const float* __restrict__ as1,
                        const float* __restrict__ ad1, const float* __restrict__ We1,
                        const float* __restrict__ ae1, const float* __restrict__ W2,
                        const float* __restrict__ as2, const float* __restrict__ ad2,
                        const float* __restrict__ We2, const float* __restrict__ ae2,
                        float* __restrict__ wa_s1, float* __restrict__ wa_d1,
                        float* __restrict__ we_a1, float* __restrict__ wa_s2,
                        float* __restrict__ wa_d2, float* __restrict__ we_a2){
  int b = blockIdx.x, lane = threadIdx.x;
  const float *W, *v1, *v2; float *o1, *o2; int C;
  if (b < 3072)      {          W=W1;  v1=as1; v2=ad1;     o1=wa_s1; o2=wa_d1; C=384; }
  else if (b < 6144) { b-=3072; W=We1; v1=ae1; v2=nullptr; o1=we_a1; o2=nullptr; C=384; }
  else if (b < 7680) { b-=6144; W=W2;  v1=as2; v2=ad2;     o1=wa_s2; o2=wa_d2; C=768; }
  else               { b-=7680; W=We2; v1=ae2; v2=nullptr; o1=we_a2; o2=nullptr; C=768; }
  int k = b >> 2, h = b & 3;
  const float* wr = W + (size_t)k * (4*C) + (size_t)h * C;
  const float* r1 = v1 + (size_t)h * C;
  float a1 = 0.f, a2 = 0.f;
  if (v2){
    const float* r2 = v2 + (size_t)h * C;
    for (int c = lane; c < C; c += 64){ float wv = wr[c]; a1 += wv*r1[c]; a2 += wv*r2[c]; }
  } else {
    for (int c = lane; c < C; c += 64) a1 += wr[c]*r1[c];
  }
  a1 = wsum(a1);
  if (v2) a2 = wsum(a2);
  if (lane == 0){ o1[k*NH + h] = a1; if (v2) o2[k*NH + h] = a2; }
}

// ---- prep: W2 -> B^T bf16 hi/lo.  Bt[c][h*384+k'] = W2[k'][h*768+c] --------
__global__ __launch_bounds__(256) void k_bt(const float* __restrict__ W2,
                                            unsigned short* __restrict__ Bh,
                                            unsigned short* __restrict__ Bl){
  __shared__ float tile[64][65];
  int bk = blockIdx.x * 64;   // k in [0,1536)
  int bc = blockIdx.y * 64;   // c in [0,768)
  int t = threadIdx.x;
  int cc = t & 63, kk4 = t >> 6;
#pragma unroll
  for (int i = 0; i < 16; ++i){
    int kk = kk4*16 + i;
    int k = bk + kk;
    int h = k / 384, kp = k - h*384;
    tile[kk][cc] = W2[(size_t)kp*3072 + h*768 + bc + cc];
  }
  __syncthreads();
  int kk2 = t & 63, cc4 = t >> 6;
#pragma unroll
  for (int i = 0; i < 16; ++i){
    int c2 = cc4*16 + i;
    float v = tile[kk2][c2];
    unsigned short hi = f2bf(v);
    unsigned short lo = f2bf(v - bf2f(hi));
    size_t o = (size_t)(bc + c2)*GK + bk + kk2;
    Bh[o] = hi; Bl[o] = lo;
  }
}

// ---- prep 2: table row-dots ------------------------------------------------
__global__ void k_prep2(const float* __restrict__ x_emb, const float* __restrict__ e_emb,
                        const float* __restrict__ wa_s1, const float* __restrict__ wa_d1,
                        const float* __restrict__ we_a1, const float* __restrict__ we_a2,
                        float* __restrict__ xa_s1, float* __restrict__ xa_d1,
                        float* __restrict__ ew1, float* __restrict__ ew2){
  int b = blockIdx.x, lane = threadIdx.x;
  const float *A, *wv; float* o;
  if (b < 712)        {          A=x_emb; wv=wa_s1; o=xa_s1; }
  else if (b < 1424)  { b-=712;  A=x_emb; wv=wa_d1; o=xa_d1; }
  else if (b < 1496)  { b-=1424; A=e_emb; wv=we_a1; o=ew1; }
  else                { b-=1496; A=e_emb; wv=we_a2; o=ew2; }
  int r = b >> 2, h = b & 3;
  const float* ar = A + (size_t)r * EMBD;
  float acc = 0.f;
  for (int k = lane; k < EMBD; k += 64) acc += ar[k] * wv[k*NH + h];
  acc = wsum(acc);
  if (lane == 0) o[r*NH + h] = acc;
}

// ---- xh1 = x_emb @ W1 [178,1536], 32x64 tiles, split-K=2 -------------------
__global__ __launch_bounds__(256) void k_gemm1(const float* __restrict__ A,
                                               const float* __restrict__ B,
                                               float* __restrict__ P){
  __shared__ float As[16][34];
  __shared__ float Bs[16][68];
  int t = threadIdx.x;
  int bn = blockIdx.x * 64;
  int bm = blockIdx.y * 32;
  int s  = blockIdx.z;
  float acc[2][4] = {};
  int tm = t >> 4, tn = t & 15;
  int ar = t >> 3, ac = (t & 7) * 2;
  int br = t >> 4, bc = (t & 15) * 4;
  int kend = s*384 + 384;
  for (int k0 = s*384; k0 < kend; k0 += 16){
    float a0 = 0.f, a1 = 0.f;
    if (bm + ar < 178){
      const float* ap = &A[(size_t)(bm+ar)*EMBD + k0 + ac];
      a0 = ap[0]; a1 = ap[1];
    }
    As[ac][ar] = a0; As[ac+1][ar] = a1;
    *(float4*)&Bs[br][bc] = *(const float4*)&B[(size_t)(k0+br)*1536 + bn + bc];
    __syncthreads();
#pragma unroll
    for (int k = 0; k < 16; ++k){
      float x0 = As[k][tm*2], x1 = As[k][tm*2+1];
      float4 b4 = *(const float4*)&Bs[k][tn*4];
      acc[0][0] += x0*b4.x; acc[0][1] += x0*b4.y; acc[0][2] += x0*b4.z; acc[0][3] += x0*b4.w;
      acc[1][0] += x1*b4.x; acc[1][1] += x1*b4.y; acc[1][2] += x1*b4.z; acc[1][3] += x1*b4.w;
    }
    __syncthreads();
  }
#pragma unroll
  for (int i = 0; i < 2; ++i){
    int r = bm + tm*2 + i;
    if (r < 178){
      float4 v; v.x=acc[i][0]; v.y=acc[i][1]; v.z=acc[i][2]; v.w=acc[i][3];
      *(float4*)&P[(size_t)s*178*1536 + (size_t)r*1536 + bn + tn*4] = v;
    }
  }
}

// ---- misc fused: xh1 reduce + node alpha + edge alpha + edge src pairs -----
#define S0 (178*1536/4)
#define S1 (NN*NH)
#define S2 (NE*NH)
#define S3 (NE)
__global__ void k_misc(const int* __restrict__ x, const int* __restrict__ ea,
                       const int* __restrict__ srcv,
                       const float* __restrict__ P, float* __restrict__ xh1,
                       const float* __restrict__ xa_s1, const float* __restrict__ xa_d1,
                       const float* __restrict__ ew1, const float* __restrict__ ew2,
                       float* __restrict__ asrc1, float* __restrict__ adst1,
                       float* __restrict__ eatt1, float* __restrict__ eatt2,
                       int* __restrict__ sa, int* __restrict__ sb){
  int i = blockIdx.x * blockDim.x + threadIdx.x;
  if (i < S0){
    float4 u = ((const float4*)P)[i];
    float4 v = ((const float4*)P)[S0 + i];
    float4 r; r.x=u.x+v.x; r.y=u.y+v.y; r.z=u.z+v.z; r.w=u.w+v.w;
    ((float4*)xh1)[i] = r;
  } else if (i < S0 + S1){
    int i2 = i - S0;
    int n = i2 >> 2, h = i2 & 3;
    int a = x[2*n], b = x[2*n+1];
    asrc1[i2] = xa_s1[a*NH+h] + xa_s1[b*NH+h];
    adst1[i2] = xa_d1[a*NH+h] + xa_d1[b*NH+h];
  } else if (i < S0 + S1 + S2){
    int i2 = i - S0 - S1;
    int e = i2 >> 2, h = i2 & 3;
    int a = ea[2*e], b = ea[2*e+1];
    eatt1[i2] = ew1[a*NH+h] + ew1[b*NH+h];
    eatt2[i2] = ew2[a*NH+h] + ew2[b*NH+h];
  } else if (i < S0 + S1 + S2 + S3){
    int e = i - S0 - S1 - S2;
    int s = srcv[e];
    sa[e] = x[2*s]; sb[e] = x[2*s+1];
  }
}

// ---- fused softmax (wave-per-head) -----------------------------------------
__device__ void gat_softmax(int n, int lo, int hi, int w, int lane, bool big,
                            const int* __restrict__ csr, const int* __restrict__ srcv,
                            const int* __restrict__ sa, const int* __restrict__ sb,
                            const float* __restrict__ asrc, const float* __restrict__ adst,
                            float* eatt, float (*wts)[4], int* sA, int* sB, float* wl){
  int deg = hi - lo;
  float ad_n = adst[n*NH + w];
  float as_n = asrc[n*NH + w];
  float mx = -3.4e38f, sae = 0.f;
  if (!big){
    for (int p = lo + lane; p < hi; p += 64){
      int e = csr[p]; int s = srcv[e];
      if (w == 0){ if (sA){ sA[p - lo] = sa[e]; sB[p - lo] = sb[e]; } }
      float ae = eatt[e*NH + w];
      float al = asrc[s*NH + w] + ad_n + ae;
      al = (al > 0.f) ? al : NEG * al;
      wts[p - lo][w] = al;
      sae += ae; mx = fmaxf(mx, al);
    }
    mx = wmax(mx); sae = wsum(sae);
    float all_ = as_n + ad_n + sae / fmaxf((float)deg, 1.f);
    all_ = (all_ > 0.f) ? all_ : NEG * all_;
    mx = fmaxf(mx, all_);
    float den = 0.f;
    for (int p = lo + lane; p < hi; p += 64){
      float xx = expf(wts[p - lo][w] - mx);
      wts[p - lo][w] = xx; den += xx;
    }
    den = wsum(den);
    float exl = expf(all_ - mx);
    den += exl;
    float inv = 1.f / den;
    for (int p = lo + lane; p < hi; p += 64) wts[p - lo][w] *= inv;
    if (lane == 0) wl[w] = exl * inv;
  } else {
    for (int p = lo + lane; p < hi; p += 64){
      int e = csr[p];
      float ae = eatt[e*NH + w];
      float al = asrc[srcv[e]*NH + w] + ad_n + ae;
      al = (al > 0.f) ? al : NEG * al;
      eatt[e*NH + w] = al;
      sae += ae; mx = fmaxf(mx, al);
    }
    mx = wmax(mx); sae = wsum(sae);
    float all_ = as_n + ad_n + sae / fmaxf((float)deg, 1.f);
    all_ = (all_ > 0.f) ? all_ : NEG * all_;
    mx = fmaxf(mx, all_);
    float den = 0.f;
    for (int p = lo + lane; p < hi; p += 64){
      int e = csr[p];
      float xx = expf(eatt[e*NH + w] - mx);
      eatt[e*NH + w] = xx; den += xx;
    }
    den = wsum(den);
    float exl = expf(all_ - mx);
    den += exl;
    float inv = 1.f / den;
    for (int p = lo + lane; p < hi; p += 64) eatt[csr[p]*NH + w] *= inv;
    if (lane == 0) wl[w] = exl * inv;
  }
}

// ---- layer-1 fused: softmax + agg from the hot xh1 table + alpha2 dots -----
__global__ __launch_bounds__(384) void k_gat1(const int* __restrict__ offsets,
                      const int* __restrict__ csr, const int* __restrict__ srcv,
                      const int* __restrict__ sa, const int* __restrict__ sb,
                      const int* __restrict__ x,
                      const float* __restrict__ asrc, const float* __restrict__ adst,
                      float* eatt, const float* __restrict__ xh1,
                      const float* __restrict__ b1, const float* __restrict__ wa_s2,
                      const float* __restrict__ wa_d2, float* __restrict__ hact,
                      float* __restrict__ asrc2, float* __restrict__ adst2){
  __shared__ float wts[DCAP][4];
  __shared__ int   sA[DCAP], sB[DCAP];
  __shared__ float wl[4];
  __shared__ float red[6][8];
  int n = blockIdx.x, t = threadIdx.x;
  int w = t >> 6, lane = t & 63;
  int lo = offsets[n], hi = offsets[n+1];
  int deg = hi - lo;
  bool big = deg > DCAP;
  if (w < 4) gat_softmax(n, lo, hi, w, lane, big, csr, srcv, sa, sb, asrc, adst,
                         eatt, wts, sA, sB, wl);
  __syncthreads();

  int c = t;  // 0..383
  float acc = 0.f;
  for (int j = 0; j < deg; ++j){
    int a, b; float w0, w1, w2, w3;
    if (big){ int e = csr[lo+j]; a = sa[e]; b = sb[e];
      w0 = eatt[e*4+0]; w1 = eatt[e*4+1]; w2 = eatt[e*4+2]; w3 = eatt[e*4+3];
    } else { a = sA[j]; b = sB[j];
      w0 = wts[j][0]; w1 = wts[j][1]; w2 = wts[j][2]; w3 = wts[j][3]; }
    const float* pa = xh1 + (size_t)a*1536 + c;
    const float* pb = xh1 + (size_t)b*1536 + c;
    acc += w0*(pa[0]+pb[0]) + w1*(pa[384]+pb[384])
         + w2*(pa[768]+pb[768]) + w3*(pa[1152]+pb[1152]);
  }
  {
    int a = x[2*n], b = x[2*n+1];
    const float* pa = xh1 + (size_t)a*1536 + c;
    const float* pb = xh1 + (size_t)b*1536 + c;
    acc += wl[0]*(pa[0]+pb[0]) + wl[1]*(pa[384]+pb[384])
         + wl[2]*(pa[768]+pb[768]) + wl[3]*(pa[1152]+pb[1152]);
  }
  float v = fmaxf(0.25f*acc + b1[c], 0.f);
  hact[n*HID + c] = v;

  float pr[8];
#pragma unroll
  for (int h = 0; h < 4; ++h){ pr[h] = v * wa_s2[c*4+h]; pr[4+h] = v * wa_d2[c*4+h]; }
#pragma unroll
  for (int o = 32; o > 0; o >>= 1){
#pragma unroll
    for (int q = 0; q < 8; ++q) pr[q] += __shfl_xor(pr[q], o, 64);
  }
  if (lane == 0){
#pragma unroll
    for (int q = 0; q < 8; ++q) red[w][q] = pr[q];
  }
  __syncthreads();
  if (t < 8){
    float s2 = 0.f;
#pragma unroll
    for (int ww = 0; ww < 6; ++ww) s2 += red[ww][t];
    if (t < 4) asrc2[n*4 + t] = s2; else adst2[n*4 + t - 4] = s2;
  }
}

// ---- layer-2 fused: softmax + agg -> G as bf16 hi/lo -----------------------
__global__ __launch_bounds__(384) void k_gat2(const int* __restrict__ offsets,
                      const int* __restrict__ csr, const int* __restrict__ srcv,
                      const float* __restrict__ asrc, const float* __restrict__ adst,
                      float* eatt, const float* __restrict__ hact,
                      unsigned short* __restrict__ Gh, unsigned short* __restrict__ Gl){
  __shared__ float wts[DCAP][4];
  __shared__ int   ssrc[DCAP];
  __shared__ float wl[4];
  int n = blockIdx.x, t = threadIdx.x;
  int w = t >> 6, lane = t & 63;
  int lo = offsets[n], hi = offsets[n+1];
  int deg = hi - lo;
  bool big = deg > DCAP;
  if (w < 4){
    float ad_n = adst[n*NH + w];
    float as_n = asrc[n*NH + w];
    float mx = -3.4e38f, sae = 0.f;
    if (!big){
      for (int p = lo + lane; p < hi; p += 64){
        int e = csr[p]; int s = srcv[e];
        if (w == 0) ssrc[p - lo] = s;
        float ae = eatt[e*NH + w];
        float al = asrc[s*NH + w] + ad_n + ae;
        al = (al > 0.f) ? al : NEG * al;
        wts[p - lo][w] = al;
        sae += ae; mx = fmaxf(mx, al);
      }
      mx = wmax(mx); sae = wsum(sae);
      float all_ = as_n + ad_n + sae / fmaxf((float)deg, 1.f);
      all_ = (all_ > 0.f) ? all_ : NEG * all_;
      mx = fmaxf(mx, all_);
      float den = 0.f;
      for (int p = lo + lane; p < hi; p += 64){
        float xx = expf(wts[p - lo][w] - mx);
        wts[p - lo][w] = xx; den += xx;
      }
      den = wsum(den);
      float exl = expf(all_ - mx);
      den += exl;
      float inv = 1.f / den;
      for (int p = lo + lane; p < hi; p += 64) wts[p - lo][w] *= inv;
      if (lane == 0) wl[w] = exl * inv;
    } else {
      gat_softmax(n, lo, hi, w, lane, true, csr, srcv, nullptr, nullptr,
                  asrc, adst, eatt, wts, nullptr, nullptr, wl);
    }
  }
  __syncthreads();

  int c = t;
  float a0 = 0.f, a1 = 0.f, a2 = 0.f, a3 = 0.f;
  for (int j = 0; j < deg; ++j){
    int s; float w0, w1, w2, w3;
    if (big){ int e = csr[lo+j]; s = srcv[e];
      w0 = eatt[e*4+0]; w1 = eatt[e*4+1]; w2 = eatt[e*4+2]; w3 = eatt[e*4+3];
    } else { s = ssrc[j]; w0 = wts[j][0]; w1 = wts[j][1]; w2 = wts[j][2]; w3 = wts[j][3]; }
    float v = hact[(size_t)s*HID + c];
    a0 += w0*v; a1 += w1*v; a2 += w2*v; a3 += w3*v;
  }
  {
    float v = hact[(size_t)n*HID + c];
    a0 += wl[0]*v; a1 += wl[1]*v; a2 += wl[2]*v; a3 += wl[3]*v;
  }
  size_t base = (size_t)n*GK + c;
  float vv[4] = {a0, a1, a2, a3};
#pragma unroll
  for (int h = 0; h < 4; ++h){
    unsigned short hi16 = f2bf(vv[h]);
    unsigned short lo16 = f2bf(vv[h] - bf2f(hi16));
    Gh[base + h*384] = hi16;
    Gl[base + h*384] = lo16;
  }
}

// ---- layer-2 MFMA GEMM v2: LDS-staged, double-buffered, XOR-swizzled -------
// out = 0.25*(G @ Bt^T) + b2, bf16 3-product. BM=BN=64, BK=64, 4 waves (2x2).
// grid 384 = 32 bm x 12 bn; XCD owns 4 consecutive bm rows (A slice L2-hot).
__global__ __launch_bounds__(256) void k_mm2(const unsigned short* __restrict__ Gh,
                                             const unsigned short* __restrict__ Gl,
                                             const unsigned short* __restrict__ Bh,
                                             const unsigned short* __restrict__ Bl,
                                             const float* __restrict__ b2,
                                             float* __restrict__ out){
  // lds[buf][mat][row][64]: mat 0=Ah 1=Al 2=Bh 3=Bl; 16B slot s_phys holds
  // logical slot s_phys ^ (row&7)  (T2 swizzle, both-sides rule #21)
  __shared__ __align__(16) unsigned short lds[2][4][64][64];   // 64 KB
  int b = blockIdx.x;
  int xcd = b & 7, idx = b >> 3;            // idx in [0,48)
  int bm = xcd*4 + idx/12, bn = idx % 12;
  int wave = threadIdx.x >> 6, lane = threadIdx.x & 63;
  int wm = wave >> 1, wn = wave & 1;
  int rl = lane & 15, kq = lane >> 4;

  // staging: wave w fills mat w. 8 instrs x (64 lanes x 16B) = 64 rows.
  int rt   = lane >> 3;                      // row-in-group 0..7
  int kswz = ((lane & 7) ^ rt) * 8;          // pre-swizzled k-offset (bf16 elems)
  const unsigned short* sbase;
  int rowbase;
  if (wave == 0){ sbase = Gh; rowbase = bm*64; }
  else if (wave == 1){ sbase = Gl; rowbase = bm*64; }
  else if (wave == 2){ sbase = Bh; rowbase = bn*64; }
  else { sbase = Bl; rowbase = bn*64; }
  bool isA = wave < 2;

  f32x4 acc[2][2] = {};

  // prologue: stage K-step 0 into buf 0
#pragma unroll
  for (int i = 0; i < 8; ++i){
    int row = rowbase + i*8 + rt;
    if (isA) row = (row < GM) ? row : (GM-1);
    gload16(sbase + (size_t)row*GK + kswz, &lds[0][wave][i*8][0]);
  }
  __syncthreads();

  for (int t = 0; t < 24; ++t){
    int cur = t & 1;
    if (t < 23){
      int k0 = (t+1)*64;
#pragma unroll
      for (int i = 0; i < 8; ++i){
        int row = rowbase + i*8 + rt;
        if (isA) row = (row < GM) ? row : (GM-1);
        gload16(sbase + (size_t)row*GK + k0 + kswz, &lds[cur^1][wave][i*8][0]);
      }
    }
#pragma unroll
    for (int ks = 0; ks < 2; ++ks){
      bf16x8 ah[2], al2[2], bh2[2], bl2[2];
#pragma unroll
      for (int i = 0; i < 2; ++i){
        int r = wm*32 + i*16 + rl;
        int sl = (ks*4 + kq) ^ (r & 7);
        ah[i]  = *(const bf16x8*)&lds[cur][0][r][sl*8];
        al2[i] = *(const bf16x8*)&lds[cur][1][r][sl*8];
      }
#pragma unroll
      for (int j = 0; j < 2; ++j){
        int cdx = wn*32 + j*16 + rl;
        int sl = (ks*4 + kq) ^ (cdx & 7);
        bh2[j] = *(const bf16x8*)&lds[cur][2][cdx][sl*8];
        bl2[j] = *(const bf16x8*)&lds[cur][3][cdx][sl*8];
      }
#pragma unroll
      for (int i = 0; i < 2; ++i){
#pragma unroll
        for (int j = 0; j < 2; ++j){
          acc[i][j] = __builtin_amdgcn_mfma_f32_16x16x32_bf16(ah[i],  bh2[j], acc[i][j], 0, 0, 0);
          acc[i][j] = __builtin_amdgcn_mfma_f32_16x16x32_bf16(ah[i],  bl2[j], acc[i][j], 0, 0, 0);
          acc[i][j] = __builtin_amdgcn_mfma_f32_16x16x32_bf16(al2[i], bh2[j], acc[i][j], 0, 0, 0);
        }
      }
    }
    __syncthreads();   // drains vmcnt (next buf staged) + lgkm (our ds_reads)
  }

#pragma unroll
  for (int i = 0; i < 2; ++i){
#pragma unroll
    for (int j = 0; j < 2; ++j){
      int col = bn*64 + wn*32 + j*16 + rl;
      float bb = b2[col];
#pragma unroll
      for (int r = 0; r < 4; ++r){
        int row = bm*64 + wm*32 + i*16 + kq*4 + r;
        if (row < GM) out[(size_t)row*GN + col] = 0.25f*acc[i][j][r] + bb;
      }
    }
  }
}

// ---------------------------------------------------------------------------
extern "C" void kernel_launch(void* const* d_in, const int* in_sizes, int n_in,
                              void* d_out, int out_size, void* d_ws, size_t ws_size,
                              hipStream_t stream){
  const int*   x     = (const int*)d_in[0];
  const int*   ei    = (const int*)d_in[1];
  const int*   ea    = (const int*)d_in[2];
  const float* x_emb = (const float*)d_in[3];
  const float* e_emb = (const float*)d_in[4];
  const float* W1    = (const float*)d_in[5];
  const float* as1   = (const float*)d_in[6];
  const float* ad1   = (const float*)d_in[7];
  const float* We1   = (const float*)d_in[8];
  const float* ae1   = (const float*)d_in[9];
  const float* b1    = (const float*)d_in[10];
  const float* W2    = (const float*)d_in[11];
  const float* as2   = (const float*)d_in[12];
  const float* ad2   = (const float*)d_in[13];
  const float* We2   = (const float*)d_in[14];
  const float* ae2   = (const float*)d_in[15];
  const float* b2    = (const float*)d_in[16];
  const int* srcv = ei;
  const int* dstv = ei + NE;
  float* out = (float*)d_out;

  char* p = (char*)d_ws;
  auto take = [&](size_t n){ void* q = (void*)p; p += (n + 255) & ~(size_t)255; return q; };
  int*   counts  = (int*)take(NN*4);
  int*   offsets = (int*)take((NN+1)*4);
  int*   cursor  = (int*)take(NN*4);
  int*   csr     = (int*)take(NE*4);
  float* wa_s1   = (float*)take(EMBD*NH*4);
  float* wa_d1   = (float*)take(EMBD*NH*4);
  float* we_a1   = (float*)take(EMBD*NH*4);
  float* wa_s2   = (float*)take(HID*NH*4);
  float* wa_d2   = (float*)take(HID*NH*4);
  float* we_a2   = (float*)take(EMBD*NH*4);
  float* xa_s1   = (float*)take(178*NH*4);
  float* xa_d1   = (float*)take(178*NH*4);
  float* ew1     = (float*)take(18*NH*4);
  float* ew2     = (float*)take(18*NH*4);
  float* xh1     = (float*)take((size_t)178*1536*4);
  float* parts1  = (float*)take((size_t)2*178*1536*4);
  unsigned short* Bth = (unsigned short*)take((size_t)GN*GK*2);
  unsigned short* Btl = (unsigned short*)take((size_t)GN*GK*2);
  unsigned short* Gh  = (unsigned short*)take((size_t)GM*GK*2);
  unsigned short* Gl  = (unsigned short*)take((size_t)GM*GK*2);
  int*   sa      = (int*)take(NE*4);
  int*   sb      = (int*)take(NE*4);
  float* eatt1   = (float*)take((size_t)NE*NH*4);
  float* eatt2   = (float*)take((size_t)NE*NH*4);
  float* hact    = (float*)take((size_t)NN*HID*4);
  float* asrc1   = (float*)take(NN*NH*4);
  float* adst1   = (float*)take(NN*NH*4);
  float* asrc2   = (float*)take(NN*NH*4);
  float* adst2   = (float*)take(NN*NH*4);

  // CSR (deterministic after in-bucket sort)
  hipMemsetAsync(counts, 0, NN*4, stream);
  k_count<<<(NE+255)/256, 256, 0, stream>>>(dstv, counts);
  k_scan<<<1, 1024, 0, stream>>>(counts, offsets, cursor);
  k_fill<<<(NE+255)/256, 256, 0, stream>>>(dstv, cursor, csr);
  k_sort<<<(NN+255)/256, 256, 0, stream>>>(offsets, csr);

  // prep
  k_prep1<<<10752, 64, 0, stream>>>(W1, as1, ad1, We1, ae1, W2, as2, ad2,
                                    We2, ae2, wa_s1, wa_d1, we_a1, wa_s2,
                                    wa_d2, we_a2);
  { dim3 g(GK/64, GN/64); k_bt<<<g, 256, 0, stream>>>(W2, Bth, Btl); }
  k_prep2<<<1568, 64, 0, stream>>>(x_emb, e_emb, wa_s1, wa_d1, we_a1, we_a2,
                                   xa_s1, xa_d1, ew1, ew2);

  // xh1 = x_emb @ W1 (split-K=2)
  { dim3 g(24, 6, 2); k_gemm1<<<g, 256, 0, stream>>>(x_emb, W1, parts1); }

  // fused elementwise (xh1 reduce, alpha terms, src pairs)
  k_misc<<<(S0+S1+S2+S3 + 255)/256, 256, 0, stream>>>(
      x, ea, srcv, parts1, xh1, xa_s1, xa_d1, ew1, ew2,
      asrc1, adst1, eatt1, eatt2, sa, sb);

  // layer 1 fused -> hact, asrc2, adst2
  k_gat1<<<NN, 384, 0, stream>>>(offsets, csr, srcv, sa, sb, x, asrc1, adst1,
                                 eatt1, xh1, b1, wa_s2, wa_d2, hact, asrc2, adst2);

  // layer 2 fused agg-first -> G (bf16 hi/lo)
  k_gat2<<<NN, 384, 0, stream>>>(offsets, csr, srcv, asrc2, adst2, eatt2, hact, Gh, Gl);

  // out = 0.25*(G @ Bt^T) + b2 via LDS-staged bf16 3-product MFMA
  k_mm2<<<384, 256, 0, stream>>>(Gh, Gl, Bth, Btl, b2, out);
}

// Round 5
// 147.814 us; speedup vs baseline: 2.9892x; 1.4065x over previous
//
#include <hip/hip_runtime.h>
#include <hip/hip_bf16.h>

#define NN   2000
#define NE   32000
#define EMBD 768
#define NH   4
#define HID  384
#define FTD  768
#define NEG  0.2f
#define DCAP 1024

#define GM 2000
#define GN 768
#define GK 1536

typedef __bf16 bf16x8 __attribute__((ext_vector_type(8)));
typedef float  f32x4  __attribute__((ext_vector_type(4)));

__device__ inline float wsum(float v){
#pragma unroll
  for (int o = 32; o > 0; o >>= 1) v += __shfl_xor(v, o, 64);
  return v;
}
__device__ inline float wmax(float v){
#pragma unroll
  for (int o = 32; o > 0; o >>= 1) v = fmaxf(v, __shfl_xor(v, o, 64));
  return v;
}

// bf16 round-to-nearest-even split helpers
__device__ inline unsigned short f2bf(float f){
  unsigned u = __float_as_uint(f);
  unsigned r = (u + 0x7FFFu + ((u >> 16) & 1u)) >> 16;
  return (unsigned short)r;
}
__device__ inline float bf2f(unsigned short h){
  return __uint_as_float(((unsigned)h) << 16);
}

__device__ inline void gload16(const void* g, void* l){
  __builtin_amdgcn_global_load_lds((const __attribute__((address_space(1))) void*)g,
                                   (__attribute__((address_space(3))) void*)l, 16, 0, 0);
}

// ---- CSR build -------------------------------------------------------------
__global__ void k_count(const int* __restrict__ dst, int* __restrict__ counts){
  int e = blockIdx.x * blockDim.x + threadIdx.x;
  if (e < NE) atomicAdd(&counts[dst[e]], 1);
}

__global__ void k_scan(const int* __restrict__ counts, int* __restrict__ offsets,
                       int* __restrict__ cursor){
  __shared__ int s[1024];
  int t = threadIdx.x;
  int a = (2*t   < NN) ? counts[2*t  ] : 0;
  int b = (2*t+1 < NN) ? counts[2*t+1] : 0;
  s[t] = a + b;
  __syncthreads();
  for (int off = 1; off < 1024; off <<= 1){
    int v = (t >= off) ? s[t-off] : 0;
    __syncthreads();
    s[t] += v;
    __syncthreads();
  }
  int base = (t > 0) ? s[t-1] : 0;
  if (2*t < NN){ offsets[2*t] = base; cursor[2*t] = base; }
  if (2*t+1 < NN){ offsets[2*t+1] = base + a; cursor[2*t+1] = base + a; }
  if (2*t == NN) offsets[NN] = base;
}

__global__ void k_fill(const int* __restrict__ dst, int* __restrict__ cursor,
                       int* __restrict__ csr){
  int e = blockIdx.x * blockDim.x + threadIdx.x;
  if (e < NE){
    int p = atomicAdd(&cursor[dst[e]], 1);
    csr[p] = e;
  }
}

// per-node LDS bitonic sort (canonical ascending order -> deterministic sums)
__global__ __launch_bounds__(256) void k_sort(const int* __restrict__ offsets,
                                              int* __restrict__ csr){
  __shared__ int s[1024];
  int n = blockIdx.x;
  int lo = offsets[n], hi = offsets[n+1];
  int deg = hi - lo;
  if (deg <= 1) return;
  if (deg > 1024){                      // safety fallback, never expected
    if (threadIdx.x == 0){
      for (int i = lo+1; i < hi; ++i){
        int v = csr[i], j = i-1;
        while (j >= lo && csr[j] > v){ csr[j+1] = csr[j]; --j; }
        csr[j+1] = v;
      }
    }
    return;
  }
  int m = 1; while (m < deg) m <<= 1;
  for (int i = threadIdx.x; i < m; i += 256)
    s[i] = (i < deg) ? csr[lo + i] : 0x7fffffff;
  __syncthreads();
  for (int k = 2; k <= m; k <<= 1){
    for (int j = k >> 1; j > 0; j >>= 1){
      for (int i = threadIdx.x; i < m; i += 256){
        int ixj = i ^ j;
        if (ixj > i){
          int a = s[i], b = s[ixj];
          bool up = ((i & k) == 0);
          if ((a > b) == up){ s[i] = b; s[ixj] = a; }
        }
      }
      __syncthreads();
    }
  }
  for (int i = threadIdx.x; i < deg; i += 256) csr[lo + i] = s[i];
}

// ---- prep 1: weight collapses, paired (read W once, dot 2 vectors) ---------
__global__ void k_prep1(const float* __restrict__ W1,  const float* __restrict__ as1,
                        const float* __restrict__ ad1, const float* __restrict__ We1,
                        const float* __restrict__ ae1, const float* __restrict__ W2,
                        const float* __restrict__ as2, const float* __restrict__ ad2,
                        const float* __restrict__ We2, const float* __restrict__ ae2,
                        float* __restrict__ wa_s1, float* __restrict__ wa_d1,
                        float* __restrict__ we_a1, float* __restrict__ wa_s2,
                        float* __restrict__ wa_d2, float* __restrict__ we_a2){
  int b = blockIdx.x, lane = threadIdx.x;
  const float *W, *v1, *v2; float *o1, *o2; int C;
  if (b < 3072)      {          W=W1;  v1=as1; v2=ad1;     o1=wa_s1; o2=wa_d1; C=384; }
  else if (b < 6144) { b-=3072; W=We1; v1=ae1; v2=nullptr; o1=we_a1; o2=nullptr; C=384; }
  else if (b < 7680) { b-=6144; W=W2;  v1=as2; v2=ad2;     o1=wa_s2; o2=wa_d2; C=768; }
  else               { b-=7680; W=We2; v1=ae2; v2=nullptr; o1=we_a2; o2=nullptr; C=768; }
  int k = b >> 2, h = b & 3;
  const float* wr = W + (size_t)k * (4*C) + (size_t)h * C;
  const float* r1 = v1 + (size_t)h * C;
  float a1 = 0.f, a2 = 0.f;
  if (v2){
    const float* r2 = v2 + (size_t)h * C;
    for (int c = lane; c < C; c += 64){ float wv = wr[c]; a1 += wv*r1[c]; a2 += wv*r2[c]; }
  } else {
    for (int c = lane; c < C; c += 64) a1 += wr[c]*r1[c];
  }
  a1 = wsum(a1);
  if (v2) a2 = wsum(a2);
  if (lane == 0){ o1[k*NH + h] = a1; if (v2) o2[k*NH + h] = a2; }
}

// ---- prep: W2 -> B^T bf16 hi/lo.  Bt[c][h*384+k'] = W2[k'][h*768+c] --------
__global__ __launch_bounds__(256) void k_bt(const float* __restrict__ W2,
                                            unsigned short* __restrict__ Bh,
                                            unsigned short* __restrict__ Bl){
  __shared__ float tile[64][65];
  int bk = blockIdx.x * 64;   // k in [0,1536)
  int bc = blockIdx.y * 64;   // c in [0,768)
  int t = threadIdx.x;
  int cc = t & 63, kk4 = t >> 6;
#pragma unroll
  for (int i = 0; i < 16; ++i){
    int kk = kk4*16 + i;
    int k = bk + kk;
    int h = k / 384, kp = k - h*384;
    tile[kk][cc] = W2[(size_t)kp*3072 + h*768 + bc + cc];
  }
  __syncthreads();
  int kk2 = t & 63, cc4 = t >> 6;
#pragma unroll
  for (int i = 0; i < 16; ++i){
    int c2 = cc4*16 + i;
    float v = tile[kk2][c2];
    unsigned short hi = f2bf(v);
    unsigned short lo = f2bf(v - bf2f(hi));
    size_t o = (size_t)(bc + c2)*GK + bk + kk2;
    Bh[o] = hi; Bl[o] = lo;
  }
}

// ---- prep 2: table row-dots ------------------------------------------------
__global__ void k_prep2(const float* __restrict__ x_emb, const float* __restrict__ e_emb,
                        const float* __restrict__ wa_s1, const float* __restrict__ wa_d1,
                        const float* __restrict__ we_a1, const float* __restrict__ we_a2,
                        float* __restrict__ xa_s1, float* __restrict__ xa_d1,
                        float* __restrict__ ew1, float* __restrict__ ew2){
  int b = blockIdx.x, lane = threadIdx.x;
  const float *A, *wv; float* o;
  if (b < 712)        {          A=x_emb; wv=wa_s1; o=xa_s1; }
  else if (b < 1424)  { b-=712;  A=x_emb; wv=wa_d1; o=xa_d1; }
  else if (b < 1496)  { b-=1424; A=e_emb; wv=we_a1; o=ew1; }
  else                { b-=1496; A=e_emb; wv=we_a2; o=ew2; }
  int r = b >> 2, h = b & 3;
  const float* ar = A + (size_t)r * EMBD;
  float acc = 0.f;
  for (int k = lane; k < EMBD; k += 64) acc += ar[k] * wv[k*NH + h];
  acc = wsum(acc);
  if (lane == 0) o[r*NH + h] = acc;
}

// ---- xh1 = x_emb @ W1 [178,1536], 32x64 tiles, split-K=2 -------------------
__global__ __launch_bounds__(256) void k_gemm1(const float* __restrict__ A,
                                               const float* __restrict__ B,
                                               float* __restrict__ P){
  __shared__ float As[16][34];
  __shared__ float Bs[16][68];
  int t = threadIdx.x;
  int bn = blockIdx.x * 64;
  int bm = blockIdx.y * 32;
  int s  = blockIdx.z;
  float acc[2][4] = {};
  int tm = t >> 4, tn = t & 15;
  int ar = t >> 3, ac = (t & 7) * 2;
  int br = t >> 4, bc = (t & 15) * 4;
  int kend = s*384 + 384;
  for (int k0 = s*384; k0 < kend; k0 += 16){
    float a0 = 0.f, a1 = 0.f;
    if (bm + ar < 178){
      const float* ap = &A[(size_t)(bm+ar)*EMBD + k0 + ac];
      a0 = ap[0]; a1 = ap[1];
    }
    As[ac][ar] = a0; As[ac+1][ar] = a1;
    *(float4*)&Bs[br][bc] = *(const float4*)&B[(size_t)(k0+br)*1536 + bn + bc];
    __syncthreads();
#pragma unroll
    for (int k = 0; k < 16; ++k){
      float x0 = As[k][tm*2], x1 = As[k][tm*2+1];
      float4 b4 = *(const float4*)&Bs[k][tn*4];
      acc[0][0] += x0*b4.x; acc[0][1] += x0*b4.y; acc[0][2] += x0*b4.z; acc[0][3] += x0*b4.w;
      acc[1][0] += x1*b4.x; acc[1][1] += x1*b4.y; acc[1][2] += x1*b4.z; acc[1][3] += x1*b4.w;
    }
    __syncthreads();
  }
#pragma unroll
  for (int i = 0; i < 2; ++i){
    int r = bm + tm*2 + i;
    if (r < 178){
      float4 v; v.x=acc[i][0]; v.y=acc[i][1]; v.z=acc[i][2]; v.w=acc[i][3];
      *(float4*)&P[(size_t)s*178*1536 + (size_t)r*1536 + bn + tn*4] = v;
    }
  }
}

// ---- misc fused: xh1 reduce + node alpha + edge alpha + edge src pairs -----
#define S0 (178*1536/4)
#define S1 (NN*NH)
#define S2 (NE*NH)
#define S3 (NE)
__global__ void k_misc(const int* __restrict__ x, const int* __restrict__ ea,
                       const int* __restrict__ srcv,
                       const float* __restrict__ P, float* __restrict__ xh1,
                       const float* __restrict__ xa_s1, const float* __restrict__ xa_d1,
                       const float* __restrict__ ew1, const float* __restrict__ ew2,
                       float* __restrict__ asrc1, float* __restrict__ adst1,
                       float* __restrict__ eatt1, float* __restrict__ eatt2,
                       int* __restrict__ sa, int* __restrict__ sb){
  int i = blockIdx.x * blockDim.x + threadIdx.x;
  if (i < S0){
    float4 u = ((const float4*)P)[i];
    float4 v = ((const float4*)P)[S0 + i];
    float4 r; r.x=u.x+v.x; r.y=u.y+v.y; r.z=u.z+v.z; r.w=u.w+v.w;
    ((float4*)xh1)[i] = r;
  } else if (i < S0 + S1){
    int i2 = i - S0;
    int n = i2 >> 2, h = i2 & 3;
    int a = x[2*n], b = x[2*n+1];
    asrc1[i2] = xa_s1[a*NH+h] + xa_s1[b*NH+h];
    adst1[i2] = xa_d1[a*NH+h] + xa_d1[b*NH+h];
  } else if (i < S0 + S1 + S2){
    int i2 = i - S0 - S1;
    int e = i2 >> 2, h = i2 & 3;
    int a = ea[2*e], b = ea[2*e+1];
    eatt1[i2] = ew1[a*NH+h] + ew1[b*NH+h];
    eatt2[i2] = ew2[a*NH+h] + ew2[b*NH+h];
  } else if (i < S0 + S1 + S2 + S3){
    int e = i - S0 - S1 - S2;
    int s = srcv[e];
    sa[e] = x[2*s]; sb[e] = x[2*s+1];
  }
}

// ---- fused softmax (wave-per-head) -----------------------------------------
__device__ void gat_softmax(int n, int lo, int hi, int w, int lane, bool big,
                            const int* __restrict__ csr, const int* __restrict__ srcv,
                            const int* __restrict__ sa, const int* __restrict__ sb,
                            const float* __restrict__ asrc, const float* __restrict__ adst,
                            float* eatt, float (*wts)[4], int* sA, int* sB, float* wl){
  int deg = hi - lo;
  float ad_n = adst[n*NH + w];
  float as_n = asrc[n*NH + w];
  float mx = -3.4e38f, sae = 0.f;
  if (!big){
    for (int p = lo + lane; p < hi; p += 64){
      int e = csr[p]; int s = srcv[e];
      if (w == 0){ if (sA){ sA[p - lo] = sa[e]; sB[p - lo] = sb[e]; } }
      float ae = eatt[e*NH + w];
      float al = asrc[s*NH + w] + ad_n + ae;
      al = (al > 0.f) ? al : NEG * al;
      wts[p - lo][w] = al;
      sae += ae; mx = fmaxf(mx, al);
    }
    mx = wmax(mx); sae = wsum(sae);
    float all_ = as_n + ad_n + sae / fmaxf((float)deg, 1.f);
    all_ = (all_ > 0.f) ? all_ : NEG * all_;
    mx = fmaxf(mx, all_);
    float den = 0.f;
    for (int p = lo + lane; p < hi; p += 64){
      float xx = expf(wts[p - lo][w] - mx);
      wts[p - lo][w] = xx; den += xx;
    }
    den = wsum(den);
    float exl = expf(all_ - mx);
    den += exl;
    float inv = 1.f / den;
    for (int p = lo + lane; p < hi; p += 64) wts[p - lo][w] *= inv;
    if (lane == 0) wl[w] = exl * inv;
  } else {
    for (int p = lo + lane; p < hi; p += 64){
      int e = csr[p];
      float ae = eatt[e*NH + w];
      float al = asrc[srcv[e]*NH + w] + ad_n + ae;
      al = (al > 0.f) ? al : NEG * al;
      eatt[e*NH + w] = al;
      sae += ae; mx = fmaxf(mx, al);
    }
    mx = wmax(mx); sae = wsum(sae);
    float all_ = as_n + ad_n + sae / fmaxf((float)deg, 1.f);
    all_ = (all_ > 0.f) ? all_ : NEG * all_;
    mx = fmaxf(mx, all_);
    float den = 0.f;
    for (int p = lo + lane; p < hi; p += 64){
      int e = csr[p];
      float xx = expf(eatt[e*NH + w] - mx);
      eatt[e*NH + w] = xx; den += xx;
    }
    den = wsum(den);
    float exl = expf(all_ - mx);
    den += exl;
    float inv = 1.f / den;
    for (int p = lo + lane; p < hi; p += 64) eatt[csr[p]*NH + w] *= inv;
    if (lane == 0) wl[w] = exl * inv;
  }
}

// ---- layer-1 fused: softmax + agg from the hot xh1 table + alpha2 dots -----
__global__ __launch_bounds__(384) void k_gat1(const int* __restrict__ offsets,
                      const int* __restrict__ csr, const int* __restrict__ srcv,
                      const int* __restrict__ sa, const int* __restrict__ sb,
                      const int* __restrict__ x,
                      const float* __restrict__ asrc, const float* __restrict__ adst,
                      float* eatt, const float* __restrict__ xh1,
                      const float* __restrict__ b1, const float* __restrict__ wa_s2,
                      const float* __restrict__ wa_d2, float* __restrict__ hact,
                      float* __restrict__ asrc2, float* __restrict__ adst2){
  __shared__ float wts[DCAP][4];
  __shared__ int   sA[DCAP], sB[DCAP];
  __shared__ float wl[4];
  __shared__ float red[6][8];
  int n = blockIdx.x, t = threadIdx.x;
  int w = t >> 6, lane = t & 63;
  int lo = offsets[n], hi = offsets[n+1];
  int deg = hi - lo;
  bool big = deg > DCAP;
  if (w < 4) gat_softmax(n, lo, hi, w, lane, big, csr, srcv, sa, sb, asrc, adst,
                         eatt, wts, sA, sB, wl);
  __syncthreads();

  int c = t;  // 0..383
  float acc = 0.f;
  for (int j = 0; j < deg; ++j){
    int a, b; float w0, w1, w2, w3;
    if (big){ int e = csr[lo+j]; a = sa[e]; b = sb[e];
      w0 = eatt[e*4+0]; w1 = eatt[e*4+1]; w2 = eatt[e*4+2]; w3 = eatt[e*4+3];
    } else { a = sA[j]; b = sB[j];
      w0 = wts[j][0]; w1 = wts[j][1]; w2 = wts[j][2]; w3 = wts[j][3]; }
    const float* pa = xh1 + (size_t)a*1536 + c;
    const float* pb = xh1 + (size_t)b*1536 + c;
    acc += w0*(pa[0]+pb[0]) + w1*(pa[384]+pb[384])
         + w2*(pa[768]+pb[768]) + w3*(pa[1152]+pb[1152]);
  }
  {
    int a = x[2*n], b = x[2*n+1];
    const float* pa = xh1 + (size_t)a*1536 + c;
    const float* pb = xh1 + (size_t)b*1536 + c;
    acc += wl[0]*(pa[0]+pb[0]) + wl[1]*(pa[384]+pb[384])
         + wl[2]*(pa[768]+pb[768]) + wl[3]*(pa[1152]+pb[1152]);
  }
  float v = fmaxf(0.25f*acc + b1[c], 0.f);
  hact[n*HID + c] = v;

  float pr[8];
#pragma unroll
  for (int h = 0; h < 4; ++h){ pr[h] = v * wa_s2[c*4+h]; pr[4+h] = v * wa_d2[c*4+h]; }
#pragma unroll
  for (int o = 32; o > 0; o >>= 1){
#pragma unroll
    for (int q = 0; q < 8; ++q) pr[q] += __shfl_xor(pr[q], o, 64);
  }
  if (lane == 0){
#pragma unroll
    for (int q = 0; q < 8; ++q) red[w][q] = pr[q];
  }
  __syncthreads();
  if (t < 8){
    float s2 = 0.f;
#pragma unroll
    for (int ww = 0; ww < 6; ++ww) s2 += red[ww][t];
    if (t < 4) asrc2[n*4 + t] = s2; else adst2[n*4 + t - 4] = s2;
  }
}

// ---- layer-2 fused: softmax + agg -> G as bf16 hi/lo -----------------------
__global__ __launch_bounds__(384) void k_gat2(const int* __restrict__ offsets,
                      const int* __restrict__ csr, const int* __restrict__ srcv,
                      const float* __restrict__ asrc, const float* __restrict__ adst,
                      float* eatt, const float* __restrict__ hact,
                      unsigned short* __restrict__ Gh, unsigned short* __restrict__ Gl){
  __shared__ float wts[DCAP][4];
  __shared__ int   ssrc[DCAP];
  __shared__ float wl[4];
  int n = blockIdx.x, t = threadIdx.x;
  int w = t >> 6, lane = t & 63;
  int lo = offsets[n], hi = offsets[n+1];
  int deg = hi - lo;
  bool big = deg > DCAP;
  if (w < 4){
    float ad_n = adst[n*NH + w];
    float as_n = asrc[n*NH + w];
    float mx = -3.4e38f, sae = 0.f;
    if (!big){
      for (int p = lo + lane; p < hi; p += 64){
        int e = csr[p]; int s = srcv[e];
        if (w == 0) ssrc[p - lo] = s;
        float ae = eatt[e*NH + w];
        float al = asrc[s*NH + w] + ad_n + ae;
        al = (al > 0.f) ? al : NEG * al;
        wts[p - lo][w] = al;
        sae += ae; mx = fmaxf(mx, al);
      }
      mx = wmax(mx); sae = wsum(sae);
      float all_ = as_n + ad_n + sae / fmaxf((float)deg, 1.f);
      all_ = (all_ > 0.f) ? all_ : NEG * all_;
      mx = fmaxf(mx, all_);
      float den = 0.f;
      for (int p = lo + lane; p < hi; p += 64){
        float xx = expf(wts[p - lo][w] - mx);
        wts[p - lo][w] = xx; den += xx;
      }
      den = wsum(den);
      float exl = expf(all_ - mx);
      den += exl;
      float inv = 1.f / den;
      for (int p = lo + lane; p < hi; p += 64) wts[p - lo][w] *= inv;
      if (lane == 0) wl[w] = exl * inv;
    } else {
      gat_softmax(n, lo, hi, w, lane, true, csr, srcv, nullptr, nullptr,
                  asrc, adst, eatt, wts, nullptr, nullptr, wl);
    }
  }
  __syncthreads();

  int c = t;
  float a0 = 0.f, a1 = 0.f, a2 = 0.f, a3 = 0.f;
  for (int j = 0; j < deg; ++j){
    int s; float w0, w1, w2, w3;
    if (big){ int e = csr[lo+j]; s = srcv[e];
      w0 = eatt[e*4+0]; w1 = eatt[e*4+1]; w2 = eatt[e*4+2]; w3 = eatt[e*4+3];
    } else { s = ssrc[j]; w0 = wts[j][0]; w1 = wts[j][1]; w2 = wts[j][2]; w3 = wts[j][3]; }
    float v = hact[(size_t)s*HID + c];
    a0 += w0*v; a1 += w1*v; a2 += w2*v; a3 += w3*v;
  }
  {
    float v = hact[(size_t)n*HID + c];
    a0 += wl[0]*v; a1 += wl[1]*v; a2 += wl[2]*v; a3 += wl[3]*v;
  }
  size_t base = (size_t)n*GK + c;
  float vv[4] = {a0, a1, a2, a3};
#pragma unroll
  for (int h = 0; h < 4; ++h){
    unsigned short hi16 = f2bf(vv[h]);
    unsigned short lo16 = f2bf(vv[h] - bf2f(hi16));
    Gh[base + h*384] = hi16;
    Gl[base + h*384] = lo16;
  }
}

// ---- layer-2 MFMA GEMM v2: LDS-staged, double-buffered, XOR-swizzled -------
// out = 0.25*(G @ Bt^T) + b2, bf16 3-product. BM=BN=64, BK=64, 4 waves (2x2).
// grid 384 = 32 bm x 12 bn; XCD owns 4 consecutive bm rows (A slice L2-hot).
__global__ __launch_bounds__(256) void k_mm2(const unsigned short* __restrict__ Gh,
                                             const unsigned short* __restrict__ Gl,
                                             const unsigned short* __restrict__ Bh,
                                             const unsigned short* __restrict__ Bl,
                                             const float* __restrict__ b2,
                                             float* __restrict__ out){
  // lds[buf][mat][row][64]: mat 0=Ah 1=Al 2=Bh 3=Bl; 16B slot s_phys holds
  // logical slot s_phys ^ (row&7)  (T2 swizzle, both-sides rule #21)
  __shared__ __align__(16) unsigned short lds[2][4][64][64];   // 64 KB
  int b = blockIdx.x;
  int xcd = b & 7, idx = b >> 3;            // idx in [0,48)
  int bm = xcd*4 + idx/12, bn = idx % 12;
  int wave = threadIdx.x >> 6, lane = threadIdx.x & 63;
  int wm = wave >> 1, wn = wave & 1;
  int rl = lane & 15, kq = lane >> 4;

  // staging: wave w fills mat w. 8 instrs x (64 lanes x 16B) = 64 rows.
  int rt   = lane >> 3;                      // row-in-group 0..7
  int kswz = ((lane & 7) ^ rt) * 8;          // pre-swizzled k-offset (bf16 elems)
  const unsigned short* sbase;
  int rowbase;
  if (wave == 0){ sbase = Gh; rowbase = bm*64; }
  else if (wave == 1){ sbase = Gl; rowbase = bm*64; }
  else if (wave == 2){ sbase = Bh; rowbase = bn*64; }
  else { sbase = Bl; rowbase = bn*64; }
  bool isA = wave < 2;

  f32x4 acc[2][2] = {};

  // prologue: stage K-step 0 into buf 0
#pragma unroll
  for (int i = 0; i < 8; ++i){
    int row = rowbase + i*8 + rt;
    if (isA) row = (row < GM) ? row : (GM-1);
    gload16(sbase + (size_t)row*GK + kswz, &lds[0][wave][i*8][0]);
  }
  __syncthreads();

  for (int t = 0; t < 24; ++t){
    int cur = t & 1;
    if (t < 23){
      int k0 = (t+1)*64;
#pragma unroll
      for (int i = 0; i < 8; ++i){
        int row = rowbase + i*8 + rt;
        if (isA) row = (row < GM) ? row : (GM-1);
        gload16(sbase + (size_t)row*GK + k0 + kswz, &lds[cur^1][wave][i*8][0]);
      }
    }
#pragma unroll
    for (int ks = 0; ks < 2; ++ks){
      bf16x8 ah[2], al2[2], bh2[2], bl2[2];
#pragma unroll
      for (int i = 0; i < 2; ++i){
        int r = wm*32 + i*16 + rl;
        int sl = (ks*4 + kq) ^ (r & 7);
        ah[i]  = *(const bf16x8*)&lds[cur][0][r][sl*8];
        al2[i] = *(const bf16x8*)&lds[cur][1][r][sl*8];
      }
#pragma unroll
      for (int j = 0; j < 2; ++j){
        int cdx = wn*32 + j*16 + rl;
        int sl = (ks*4 + kq) ^ (cdx & 7);
        bh2[j] = *(const bf16x8*)&lds[cur][2][cdx][sl*8];
        bl2[j] = *(const bf16x8*)&lds[cur][3][cdx][sl*8];
      }
#pragma unroll
      for (int i = 0; i < 2; ++i){
#pragma unroll
        for (int j = 0; j < 2; ++j){
          acc[i][j] = __builtin_amdgcn_mfma_f32_16x16x32_bf16(ah[i],  bh2[j], acc[i][j], 0, 0, 0);
          acc[i][j] = __builtin_amdgcn_mfma_f32_16x16x32_bf16(ah[i],  bl2[j], acc[i][j], 0, 0, 0);
          acc[i][j] = __builtin_amdgcn_mfma_f32_16x16x32_bf16(al2[i], bh2[j], acc[i][j], 0, 0, 0);
        }
      }
    }
    __syncthreads();   // drains vmcnt (next buf staged) + lgkm (our ds_reads)
  }

#pragma unroll
  for (int i = 0; i < 2; ++i){
#pragma unroll
    for (int j = 0; j < 2; ++j){
      int col = bn*64 + wn*32 + j*16 + rl;
      float bb = b2[col];
#pragma unroll
      for (int r = 0; r < 4; ++r){
        int row = bm*64 + wm*32 + i*16 + kq*4 + r;
        if (row < GM) out[(size_t)row*GN + col] = 0.25f*acc[i][j][r] + bb;
      }
    }
  }
}

// ---------------------------------------------------------------------------
extern "C" void kernel_launch(void* const* d_in, const int* in_sizes, int n_in,
                              void* d_out, int out_size, void* d_ws, size_t ws_size,
                              hipStream_t stream){
  const int*   x     = (const int*)d_in[0];
  const int*   ei    = (const int*)d_in[1];
  const int*   ea    = (const int*)d_in[2];
  const float* x_emb = (const float*)d_in[3];
  const float* e_emb = (const float*)d_in[4];
  const float* W1    = (const float*)d_in[5];
  const float* as1   = (const float*)d_in[6];
  const float* ad1   = (const float*)d_in[7];
  const float* We1   = (const float*)d_in[8];
  const float* ae1   = (const float*)d_in[9];
  const float* b1    = (const float*)d_in[10];
  const float* W2    = (const float*)d_in[11];
  const float* as2   = (const float*)d_in[12];
  const float* ad2   = (const float*)d_in[13];
  const float* We2   = (const float*)d_in[14];
  const float* ae2   = (const float*)d_in[15];
  const float* b2    = (const float*)d_in[16];
  const int* srcv = ei;
  const int* dstv = ei + NE;
  float* out = (float*)d_out;

  char* p = (char*)d_ws;
  auto take = [&](size_t n){ void* q = (void*)p; p += (n + 255) & ~(size_t)255; return q; };
  int*   counts  = (int*)take(NN*4);
  int*   offsets = (int*)take((NN+1)*4);
  int*   cursor  = (int*)take(NN*4);
  int*   csr     = (int*)take(NE*4);
  float* wa_s1   = (float*)take(EMBD*NH*4);
  float* wa_d1   = (float*)take(EMBD*NH*4);
  float* we_a1   = (float*)take(EMBD*NH*4);
  float* wa_s2   = (float*)take(HID*NH*4);
  float* wa_d2   = (float*)take(HID*NH*4);
  float* we_a2   = (float*)take(EMBD*NH*4);
  float* xa_s1   = (float*)take(178*NH*4);
  float* xa_d1   = (float*)take(178*NH*4);
  float* ew1     = (float*)take(18*NH*4);
  float* ew2     = (float*)take(18*NH*4);
  float* xh1     = (float*)take((size_t)178*1536*4);
  float* parts1  = (float*)take((size_t)2*178*1536*4);
  unsigned short* Bth = (unsigned short*)take((size_t)GN*GK*2);
  unsigned short* Btl = (unsigned short*)take((size_t)GN*GK*2);
  unsigned short* Gh  = (unsigned short*)take((size_t)GM*GK*2);
  unsigned short* Gl  = (unsigned short*)take((size_t)GM*GK*2);
  int*   sa      = (int*)take(NE*4);
  int*   sb      = (int*)take(NE*4);
  float* eatt1   = (float*)take((size_t)NE*NH*4);
  float* eatt2   = (float*)take((size_t)NE*NH*4);
  float* hact    = (float*)take((size_t)NN*HID*4);
  float* asrc1   = (float*)take(NN*NH*4);
  float* adst1   = (float*)take(NN*NH*4);
  float* asrc2   = (float*)take(NN*NH*4);
  float* adst2   = (float*)take(NN*NH*4);

  // CSR (deterministic after in-bucket bitonic sort)
  hipMemsetAsync(counts, 0, NN*4, stream);
  k_count<<<(NE+255)/256, 256, 0, stream>>>(dstv, counts);
  k_scan<<<1, 1024, 0, stream>>>(counts, offsets, cursor);
  k_fill<<<(NE+255)/256, 256, 0, stream>>>(dstv, cursor, csr);
  k_sort<<<NN, 256, 0, stream>>>(offsets, csr);

  // prep
  k_prep1<<<10752, 64, 0, stream>>>(W1, as1, ad1, We1, ae1, W2, as2, ad2,
                                    We2, ae2, wa_s1, wa_d1, we_a1, wa_s2,
                                    wa_d2, we_a2);
  { dim3 g(GK/64, GN/64); k_bt<<<g, 256, 0, stream>>>(W2, Bth, Btl); }
  k_prep2<<<1568, 64, 0, stream>>>(x_emb, e_emb, wa_s1, wa_d1, we_a1, we_a2,
                                   xa_s1, xa_d1, ew1, ew2);

  // xh1 = x_emb @ W1 (split-K=2)
  { dim3 g(24, 6, 2); k_gemm1<<<g, 256, 0, stream>>>(x_emb, W1, parts1); }

  // fused elementwise (xh1 reduce, alpha terms, src pairs)
  k_misc<<<(S0+S1+S2+S3 + 255)/256, 256, 0, stream>>>(
      x, ea, srcv, parts1, xh1, xa_s1, xa_d1, ew1, ew2,
      asrc1, adst1, eatt1, eatt2, sa, sb);

  // layer 1 fused -> hact, asrc2, adst2
  k_gat1<<<NN, 384, 0, stream>>>(offsets, csr, srcv, sa, sb, x, asrc1, adst1,
                                 eatt1, xh1, b1, wa_s2, wa_d2, hact, asrc2, adst2);

  // layer 2 fused agg-first -> G (bf16 hi/lo)
  k_gat2<<<NN, 384, 0, stream>>>(offsets, csr, srcv, asrc2, adst2, eatt2, hact, Gh, Gl);

  // out = 0.25*(G @ Bt^T) + b2 via LDS-staged bf16 3-product MFMA
  k_mm2<<<384, 256, 0, stream>>>(Gh, Gl, Bth, Btl, b2, out);
}

// Round 6
// 146.673 us; speedup vs baseline: 3.0124x; 1.0078x over previous
//
#include <hip/hip_runtime.h>
#include <hip/hip_bf16.h>

#define NN   2000
#define NE   32000
#define EMBD 768
#define NH   4
#define HID  384
#define FTD  768
#define NEG  0.2f
#define DCAP 1024

#define GM 2000
#define GN 768
#define GK 1536

typedef __bf16 bf16x8 __attribute__((ext_vector_type(8)));
typedef float  f32x4  __attribute__((ext_vector_type(4)));

__device__ inline float wsum(float v){
#pragma unroll
  for (int o = 32; o > 0; o >>= 1) v += __shfl_xor(v, o, 64);
  return v;
}
__device__ inline float wmax(float v){
#pragma unroll
  for (int o = 32; o > 0; o >>= 1) v = fmaxf(v, __shfl_xor(v, o, 64));
  return v;
}

// bf16 round-to-nearest-even split helpers
__device__ inline unsigned short f2bf(float f){
  unsigned u = __float_as_uint(f);
  unsigned r = (u + 0x7FFFu + ((u >> 16) & 1u)) >> 16;
  return (unsigned short)r;
}
__device__ inline float bf2f(unsigned short h){
  return __uint_as_float(((unsigned)h) << 16);
}

__device__ inline void gload16(const void* g, void* l){
  __builtin_amdgcn_global_load_lds((const __attribute__((address_space(1))) void*)g,
                                   (__attribute__((address_space(3))) void*)l, 16, 0, 0);
}

// ---- CSR build -------------------------------------------------------------
// zero counts (replaces hipMemsetAsync: rocclr fillBufferAligned cost 42 us!)
__global__ void k_zero(int* __restrict__ counts){
  int i = blockIdx.x * blockDim.x + threadIdx.x;
  if (i < NN) counts[i] = 0;
}

__global__ void k_count(const int* __restrict__ dst, int* __restrict__ counts){
  int e = blockIdx.x * blockDim.x + threadIdx.x;
  if (e < NE) atomicAdd(&counts[dst[e]], 1);
}

__global__ void k_scan(const int* __restrict__ counts, int* __restrict__ offsets,
                       int* __restrict__ cursor){
  __shared__ int s[1024];
  int t = threadIdx.x;
  int a = (2*t   < NN) ? counts[2*t  ] : 0;
  int b = (2*t+1 < NN) ? counts[2*t+1] : 0;
  s[t] = a + b;
  __syncthreads();
  for (int off = 1; off < 1024; off <<= 1){
    int v = (t >= off) ? s[t-off] : 0;
    __syncthreads();
    s[t] += v;
    __syncthreads();
  }
  int base = (t > 0) ? s[t-1] : 0;
  if (2*t < NN){ offsets[2*t] = base; cursor[2*t] = base; }
  if (2*t+1 < NN){ offsets[2*t+1] = base + a; cursor[2*t+1] = base + a; }
  if (2*t == NN) offsets[NN] = base;
}

__global__ void k_fill(const int* __restrict__ dst, int* __restrict__ cursor,
                       int* __restrict__ csr){
  int e = blockIdx.x * blockDim.x + threadIdx.x;
  if (e < NE){
    int p = atomicAdd(&cursor[dst[e]], 1);
    csr[p] = e;
  }
}

// per-node LDS bitonic sort (canonical ascending order -> deterministic sums)
__global__ __launch_bounds__(256) void k_sort(const int* __restrict__ offsets,
                                              int* __restrict__ csr){
  __shared__ int s[1024];
  int n = blockIdx.x;
  int lo = offsets[n], hi = offsets[n+1];
  int deg = hi - lo;
  if (deg <= 1) return;
  if (deg > 1024){                      // safety fallback, never expected
    if (threadIdx.x == 0){
      for (int i = lo+1; i < hi; ++i){
        int v = csr[i], j = i-1;
        while (j >= lo && csr[j] > v){ csr[j+1] = csr[j]; --j; }
        csr[j+1] = v;
      }
    }
    return;
  }
  int m = 1; while (m < deg) m <<= 1;
  for (int i = threadIdx.x; i < m; i += 256)
    s[i] = (i < deg) ? csr[lo + i] : 0x7fffffff;
  __syncthreads();
  for (int k = 2; k <= m; k <<= 1){
    for (int j = k >> 1; j > 0; j >>= 1){
      for (int i = threadIdx.x; i < m; i += 256){
        int ixj = i ^ j;
        if (ixj > i){
          int a = s[i], b = s[ixj];
          bool up = ((i & k) == 0);
          if ((a > b) == up){ s[i] = b; s[ixj] = a; }
        }
      }
      __syncthreads();
    }
  }
  for (int i = threadIdx.x; i < deg; i += 256) csr[lo + i] = s[i];
}

// ---- prep 1: weight collapses, paired (read W once, dot 2 vectors) ---------
__global__ void k_prep1(const float* __restrict__ W1,  const float* __restrict__ as1,
                        const float* __restrict__ ad1, const float* __restrict__ We1,
                        const float* __restrict__ ae1, const float* __restrict__ W2,
                        const float* __restrict__ as2, const float* __restrict__ ad2,
                        const float* __restrict__ We2, const float* __restrict__ ae2,
                        float* __restrict__ wa_s1, float* __restrict__ wa_d1,
                        float* __restrict__ we_a1, float* __restrict__ wa_s2,
                        float* __restrict__ wa_d2, float* __restrict__ we_a2){
  int b = blockIdx.x, lane = threadIdx.x;
  const float *W, *v1, *v2; float *o1, *o2; int C;
  if (b < 3072)      {          W=W1;  v1=as1; v2=ad1;     o1=wa_s1; o2=wa_d1; C=384; }
  else if (b < 6144) { b-=3072; W=We1; v1=ae1; v2=nullptr; o1=we_a1; o2=nullptr; C=384; }
  else if (b < 7680) { b-=6144; W=W2;  v1=as2; v2=ad2;     o1=wa_s2; o2=wa_d2; C=768; }
  else               { b-=7680; W=We2; v1=ae2; v2=nullptr; o1=we_a2; o2=nullptr; C=768; }
  int k = b >> 2, h = b & 3;
  const float* wr = W + (size_t)k * (4*C) + (size_t)h * C;
  const float* r1 = v1 + (size_t)h * C;
  float a1 = 0.f, a2 = 0.f;
  if (v2){
    const float* r2 = v2 + (size_t)h * C;
    for (int c = lane; c < C; c += 64){ float wv = wr[c]; a1 += wv*r1[c]; a2 += wv*r2[c]; }
  } else {
    for (int c = lane; c < C; c += 64) a1 += wr[c]*r1[c];
  }
  a1 = wsum(a1);
  if (v2) a2 = wsum(a2);
  if (lane == 0){ o1[k*NH + h] = a1; if (v2) o2[k*NH + h] = a2; }
}

// ---- prep: W2 -> B^T bf16 hi/lo.  Bt[c][h*384+k'] = W2[k'][h*768+c] --------
__global__ __launch_bounds__(256) void k_bt(const float* __restrict__ W2,
                                            unsigned short* __restrict__ Bh,
                                            unsigned short* __restrict__ Bl){
  __shared__ float tile[64][65];
  int bk = blockIdx.x * 64;   // k in [0,1536)
  int bc = blockIdx.y * 64;   // c in [0,768)
  int t = threadIdx.x;
  int cc = t & 63, kk4 = t >> 6;
#pragma unroll
  for (int i = 0; i < 16; ++i){
    int kk = kk4*16 + i;
    int k = bk + kk;
    int h = k / 384, kp = k - h*384;
    tile[kk][cc] = W2[(size_t)kp*3072 + h*768 + bc + cc];
  }
  __syncthreads();
  int kk2 = t & 63, cc4 = t >> 6;
#pragma unroll
  for (int i = 0; i < 16; ++i){
    int c2 = cc4*16 + i;
    float v = tile[kk2][c2];
    unsigned short hi = f2bf(v);
    unsigned short lo = f2bf(v - bf2f(hi));
    size_t o = (size_t)(bc + c2)*GK + bk + kk2;
    Bh[o] = hi; Bl[o] = lo;
  }
}

// ---- prep 2: table row-dots ------------------------------------------------
__global__ void k_prep2(const float* __restrict__ x_emb, const float* __restrict__ e_emb,
                        const float* __restrict__ wa_s1, const float* __restrict__ wa_d1,
                        const float* __restrict__ we_a1, const float* __restrict__ we_a2,
                        float* __restrict__ xa_s1, float* __restrict__ xa_d1,
                        float* __restrict__ ew1, float* __restrict__ ew2){
  int b = blockIdx.x, lane = threadIdx.x;
  const float *A, *wv; float* o;
  if (b < 712)        {          A=x_emb; wv=wa_s1; o=xa_s1; }
  else if (b < 1424)  { b-=712;  A=x_emb; wv=wa_d1; o=xa_d1; }
  else if (b < 1496)  { b-=1424; A=e_emb; wv=we_a1; o=ew1; }
  else                { b-=1496; A=e_emb; wv=we_a2; o=ew2; }
  int r = b >> 2, h = b & 3;
  const float* ar = A + (size_t)r * EMBD;
  float acc = 0.f;
  for (int k = lane; k < EMBD; k += 64) acc += ar[k] * wv[k*NH + h];
  acc = wsum(acc);
  if (lane == 0) o[r*NH + h] = acc;
}

// ---- xh1 = x_emb @ W1 [178,1536], 32x64 tiles, split-K=2 -------------------
__global__ __launch_bounds__(256) void k_gemm1(const float* __restrict__ A,
                                               const float* __restrict__ B,
                                               float* __restrict__ P){
  __shared__ float As[16][34];
  __shared__ float Bs[16][68];
  int t = threadIdx.x;
  int bn = blockIdx.x * 64;
  int bm = blockIdx.y * 32;
  int s  = blockIdx.z;
  float acc[2][4] = {};
  int tm = t >> 4, tn = t & 15;
  int ar = t >> 3, ac = (t & 7) * 2;
  int br = t >> 4, bc = (t & 15) * 4;
  int kend = s*384 + 384;
  for (int k0 = s*384; k0 < kend; k0 += 16){
    float a0 = 0.f, a1 = 0.f;
    if (bm + ar < 178){
      const float* ap = &A[(size_t)(bm+ar)*EMBD + k0 + ac];
      a0 = ap[0]; a1 = ap[1];
    }
    As[ac][ar] = a0; As[ac+1][ar] = a1;
    *(float4*)&Bs[br][bc] = *(const float4*)&B[(size_t)(k0+br)*1536 + bn + bc];
    __syncthreads();
#pragma unroll
    for (int k = 0; k < 16; ++k){
      float x0 = As[k][tm*2], x1 = As[k][tm*2+1];
      float4 b4 = *(const float4*)&Bs[k][tn*4];
      acc[0][0] += x0*b4.x; acc[0][1] += x0*b4.y; acc[0][2] += x0*b4.z; acc[0][3] += x0*b4.w;
      acc[1][0] += x1*b4.x; acc[1][1] += x1*b4.y; acc[1][2] += x1*b4.z; acc[1][3] += x1*b4.w;
    }
    __syncthreads();
  }
#pragma unroll
  for (int i = 0; i < 2; ++i){
    int r = bm + tm*2 + i;
    if (r < 178){
      float4 v; v.x=acc[i][0]; v.y=acc[i][1]; v.z=acc[i][2]; v.w=acc[i][3];
      *(float4*)&P[(size_t)s*178*1536 + (size_t)r*1536 + bn + tn*4] = v;
    }
  }
}

// ---- misc fused: xh1 reduce + node alpha + edge alpha + edge src pairs -----
#define S0 (178*1536/4)
#define S1 (NN*NH)
#define S2 (NE*NH)
#define S3 (NE)
__global__ void k_misc(const int* __restrict__ x, const int* __restrict__ ea,
                       const int* __restrict__ srcv,
                       const float* __restrict__ P, float* __restrict__ xh1,
                       const float* __restrict__ xa_s1, const float* __restrict__ xa_d1,
                       const float* __restrict__ ew1, const float* __restrict__ ew2,
                       float* __restrict__ asrc1, float* __restrict__ adst1,
                       float* __restrict__ eatt1, float* __restrict__ eatt2,
                       int* __restrict__ sa, int* __restrict__ sb){
  int i = blockIdx.x * blockDim.x + threadIdx.x;
  if (i < S0){
    float4 u = ((const float4*)P)[i];
    float4 v = ((const float4*)P)[S0 + i];
    float4 r; r.x=u.x+v.x; r.y=u.y+v.y; r.z=u.z+v.z; r.w=u.w+v.w;
    ((float4*)xh1)[i] = r;
  } else if (i < S0 + S1){
    int i2 = i - S0;
    int n = i2 >> 2, h = i2 & 3;
    int a = x[2*n], b = x[2*n+1];
    asrc1[i2] = xa_s1[a*NH+h] + xa_s1[b*NH+h];
    adst1[i2] = xa_d1[a*NH+h] + xa_d1[b*NH+h];
  } else if (i < S0 + S1 + S2){
    int i2 = i - S0 - S1;
    int e = i2 >> 2, h = i2 & 3;
    int a = ea[2*e], b = ea[2*e+1];
    eatt1[i2] = ew1[a*NH+h] + ew1[b*NH+h];
    eatt2[i2] = ew2[a*NH+h] + ew2[b*NH+h];
  } else if (i < S0 + S1 + S2 + S3){
    int e = i - S0 - S1 - S2;
    int s = srcv[e];
    sa[e] = x[2*s]; sb[e] = x[2*s+1];
  }
}

// ---- fused softmax (wave-per-head) -----------------------------------------
__device__ void gat_softmax(int n, int lo, int hi, int w, int lane, bool big,
                            const int* __restrict__ csr, const int* __restrict__ srcv,
                            const int* __restrict__ sa, const int* __restrict__ sb,
                            const float* __restrict__ asrc, const float* __restrict__ adst,
                            float* eatt, float (*wts)[4], int* sA, int* sB, float* wl){
  int deg = hi - lo;
  float ad_n = adst[n*NH + w];
  float as_n = asrc[n*NH + w];
  float mx = -3.4e38f, sae = 0.f;
  if (!big){
    for (int p = lo + lane; p < hi; p += 64){
      int e = csr[p]; int s = srcv[e];
      if (w == 0){ if (sA){ sA[p - lo] = sa[e]; sB[p - lo] = sb[e]; } }
      float ae = eatt[e*NH + w];
      float al = asrc[s*NH + w] + ad_n + ae;
      al = (al > 0.f) ? al : NEG * al;
      wts[p - lo][w] = al;
      sae += ae; mx = fmaxf(mx, al);
    }
    mx = wmax(mx); sae = wsum(sae);
    float all_ = as_n + ad_n + sae / fmaxf((float)deg, 1.f);
    all_ = (all_ > 0.f) ? all_ : NEG * all_;
    mx = fmaxf(mx, all_);
    float den = 0.f;
    for (int p = lo + lane; p < hi; p += 64){
      float xx = expf(wts[p - lo][w] - mx);
      wts[p - lo][w] = xx; den += xx;
    }
    den = wsum(den);
    float exl = expf(all_ - mx);
    den += exl;
    float inv = 1.f / den;
    for (int p = lo + lane; p < hi; p += 64) wts[p - lo][w] *= inv;
    if (lane == 0) wl[w] = exl * inv;
  } else {
    for (int p = lo + lane; p < hi; p += 64){
      int e = csr[p];
      float ae = eatt[e*NH + w];
      float al = asrc[srcv[e]*NH + w] + ad_n + ae;
      al = (al > 0.f) ? al : NEG * al;
      eatt[e*NH + w] = al;
      sae += ae; mx = fmaxf(mx, al);
    }
    mx = wmax(mx); sae = wsum(sae);
    float all_ = as_n + ad_n + sae / fmaxf((float)deg, 1.f);
    all_ = (all_ > 0.f) ? all_ : NEG * all_;
    mx = fmaxf(mx, all_);
    float den = 0.f;
    for (int p = lo + lane; p < hi; p += 64){
      int e = csr[p];
      float xx = expf(eatt[e*NH + w] - mx);
      eatt[e*NH + w] = xx; den += xx;
    }
    den = wsum(den);
    float exl = expf(all_ - mx);
    den += exl;
    float inv = 1.f / den;
    for (int p = lo + lane; p < hi; p += 64) eatt[csr[p]*NH + w] *= inv;
    if (lane == 0) wl[w] = exl * inv;
  }
}

// ---- layer-1 fused: softmax + agg from the hot xh1 table + alpha2 dots -----
__global__ __launch_bounds__(384) void k_gat1(const int* __restrict__ offsets,
                      const int* __restrict__ csr, const int* __restrict__ srcv,
                      const int* __restrict__ sa, const int* __restrict__ sb,
                      const int* __restrict__ x,
                      const float* __restrict__ asrc, const float* __restrict__ adst,
                      float* eatt, const float* __restrict__ xh1,
                      const float* __restrict__ b1, const float* __restrict__ wa_s2,
                      const float* __restrict__ wa_d2, float* __restrict__ hact,
                      float* __restrict__ asrc2, float* __restrict__ adst2){
  __shared__ float wts[DCAP][4];
  __shared__ int   sA[DCAP], sB[DCAP];
  __shared__ float wl[4];
  __shared__ float red[6][8];
  int n = blockIdx.x, t = threadIdx.x;
  int w = t >> 6, lane = t & 63;
  int lo = offsets[n], hi = offsets[n+1];
  int deg = hi - lo;
  bool big = deg > DCAP;
  if (w < 4) gat_softmax(n, lo, hi, w, lane, big, csr, srcv, sa, sb, asrc, adst,
                         eatt, wts, sA, sB, wl);
  __syncthreads();

  int c = t;  // 0..383
  float acc = 0.f;
  for (int j = 0; j < deg; ++j){
    int a, b; float w0, w1, w2, w3;
    if (big){ int e = csr[lo+j]; a = sa[e]; b = sb[e];
      w0 = eatt[e*4+0]; w1 = eatt[e*4+1]; w2 = eatt[e*4+2]; w3 = eatt[e*4+3];
    } else { a = sA[j]; b = sB[j];
      w0 = wts[j][0]; w1 = wts[j][1]; w2 = wts[j][2]; w3 = wts[j][3]; }
    const float* pa = xh1 + (size_t)a*1536 + c;
    const float* pb = xh1 + (size_t)b*1536 + c;
    acc += w0*(pa[0]+pb[0]) + w1*(pa[384]+pb[384])
         + w2*(pa[768]+pb[768]) + w3*(pa[1152]+pb[1152]);
  }
  {
    int a = x[2*n], b = x[2*n+1];
    const float* pa = xh1 + (size_t)a*1536 + c;
    const float* pb = xh1 + (size_t)b*1536 + c;
    acc += wl[0]*(pa[0]+pb[0]) + wl[1]*(pa[384]+pb[384])
         + wl[2]*(pa[768]+pb[768]) + wl[3]*(pa[1152]+pb[1152]);
  }
  float v = fmaxf(0.25f*acc + b1[c], 0.f);
  hact[n*HID + c] = v;

  float pr[8];
#pragma unroll
  for (int h = 0; h < 4; ++h){ pr[h] = v * wa_s2[c*4+h]; pr[4+h] = v * wa_d2[c*4+h]; }
#pragma unroll
  for (int o = 32; o > 0; o >>= 1){
#pragma unroll
    for (int q = 0; q < 8; ++q) pr[q] += __shfl_xor(pr[q], o, 64);
  }
  if (lane == 0){
#pragma unroll
    for (int q = 0; q < 8; ++q) red[w][q] = pr[q];
  }
  __syncthreads();
  if (t < 8){
    float s2 = 0.f;
#pragma unroll
    for (int ww = 0; ww < 6; ++ww) s2 += red[ww][t];
    if (t < 4) asrc2[n*4 + t] = s2; else adst2[n*4 + t - 4] = s2;
  }
}

// ---- layer-2 fused: softmax + agg -> G as bf16 hi/lo -----------------------
__global__ __launch_bounds__(384) void k_gat2(const int* __restrict__ offsets,
                      const int* __restrict__ csr, const int* __restrict__ srcv,
                      const float* __restrict__ asrc, const float* __restrict__ adst,
                      float* eatt, const float* __restrict__ hact,
                      unsigned short* __restrict__ Gh, unsigned short* __restrict__ Gl){
  __shared__ float wts[DCAP][4];
  __shared__ int   ssrc[DCAP];
  __shared__ float wl[4];
  int n = blockIdx.x, t = threadIdx.x;
  int w = t >> 6, lane = t & 63;
  int lo = offsets[n], hi = offsets[n+1];
  int deg = hi - lo;
  bool big = deg > DCAP;
  if (w < 4){
    float ad_n = adst[n*NH + w];
    float as_n = asrc[n*NH + w];
    float mx = -3.4e38f, sae = 0.f;
    if (!big){
      for (int p = lo + lane; p < hi; p += 64){
        int e = csr[p]; int s = srcv[e];
        if (w == 0) ssrc[p - lo] = s;
        float ae = eatt[e*NH + w];
        float al = asrc[s*NH + w] + ad_n + ae;
        al = (al > 0.f) ? al : NEG * al;
        wts[p - lo][w] = al;
        sae += ae; mx = fmaxf(mx, al);
      }
      mx = wmax(mx); sae = wsum(sae);
      float all_ = as_n + ad_n + sae / fmaxf((float)deg, 1.f);
      all_ = (all_ > 0.f) ? all_ : NEG * all_;
      mx = fmaxf(mx, all_);
      float den = 0.f;
      for (int p = lo + lane; p < hi; p += 64){
        float xx = expf(wts[p - lo][w] - mx);
        wts[p - lo][w] = xx; den += xx;
      }
      den = wsum(den);
      float exl = expf(all_ - mx);
      den += exl;
      float inv = 1.f / den;
      for (int p = lo + lane; p < hi; p += 64) wts[p - lo][w] *= inv;
      if (lane == 0) wl[w] = exl * inv;
    } else {
      gat_softmax(n, lo, hi, w, lane, true, csr, srcv, nullptr, nullptr,
                  asrc, adst, eatt, wts, nullptr, nullptr, wl);
    }
  }
  __syncthreads();

  int c = t;
  float a0 = 0.f, a1 = 0.f, a2 = 0.f, a3 = 0.f;
  for (int j = 0; j < deg; ++j){
    int s; float w0, w1, w2, w3;
    if (big){ int e = csr[lo+j]; s = srcv[e];
      w0 = eatt[e*4+0]; w1 = eatt[e*4+1]; w2 = eatt[e*4+2]; w3 = eatt[e*4+3];
    } else { s = ssrc[j]; w0 = wts[j][0]; w1 = wts[j][1]; w2 = wts[j][2]; w3 = wts[j][3]; }
    float v = hact[(size_t)s*HID + c];
    a0 += w0*v; a1 += w1*v; a2 += w2*v; a3 += w3*v;
  }
  {
    float v = hact[(size_t)n*HID + c];
    a0 += wl[0]*v; a1 += wl[1]*v; a2 += wl[2]*v; a3 += wl[3]*v;
  }
  size_t base = (size_t)n*GK + c;
  float vv[4] = {a0, a1, a2, a3};
#pragma unroll
  for (int h = 0; h < 4; ++h){
    unsigned short hi16 = f2bf(vv[h]);
    unsigned short lo16 = f2bf(vv[h] - bf2f(hi16));
    Gh[base + h*384] = hi16;
    Gl[base + h*384] = lo16;
  }
}

// ---- layer-2 MFMA GEMM v2: LDS-staged, double-buffered, XOR-swizzled -------
// out = 0.25*(G @ Bt^T) + b2, bf16 3-product. BM=BN=64, BK=64, 4 waves (2x2).
// grid 384 = 32 bm x 12 bn; XCD owns 4 consecutive bm rows (A slice L2-hot).
__global__ __launch_bounds__(256) void k_mm2(const unsigned short* __restrict__ Gh,
                                             const unsigned short* __restrict__ Gl,
                                             const unsigned short* __restrict__ Bh,
                                             const unsigned short* __restrict__ Bl,
                                             const float* __restrict__ b2,
                                             float* __restrict__ out){
  // lds[buf][mat][row][64]: mat 0=Ah 1=Al 2=Bh 3=Bl; 16B slot s_phys holds
  // logical slot s_phys ^ (row&7)  (T2 swizzle, both-sides rule #21)
  __shared__ __align__(16) unsigned short lds[2][4][64][64];   // 64 KB
  int b = blockIdx.x;
  int xcd = b & 7, idx = b >> 3;            // idx in [0,48)
  int bm = xcd*4 + idx/12, bn = idx % 12;
  int wave = threadIdx.x >> 6, lane = threadIdx.x & 63;
  int wm = wave >> 1, wn = wave & 1;
  int rl = lane & 15, kq = lane >> 4;

  // staging: wave w fills mat w. 8 instrs x (64 lanes x 16B) = 64 rows.
  int rt   = lane >> 3;                      // row-in-group 0..7
  int kswz = ((lane & 7) ^ rt) * 8;          // pre-swizzled k-offset (bf16 elems)
  const unsigned short* sbase;
  int rowbase;
  if (wave == 0){ sbase = Gh; rowbase = bm*64; }
  else if (wave == 1){ sbase = Gl; rowbase = bm*64; }
  else if (wave == 2){ sbase = Bh; rowbase = bn*64; }
  else { sbase = Bl; rowbase = bn*64; }
  bool isA = wave < 2;

  f32x4 acc[2][2] = {};

  // prologue: stage K-step 0 into buf 0
#pragma unroll
  for (int i = 0; i < 8; ++i){
    int row = rowbase + i*8 + rt;
    if (isA) row = (row < GM) ? row : (GM-1);
    gload16(sbase + (size_t)row*GK + kswz, &lds[0][wave][i*8][0]);
  }
  __syncthreads();

  for (int t = 0; t < 24; ++t){
    int cur = t & 1;
    if (t < 23){
      int k0 = (t+1)*64;
#pragma unroll
      for (int i = 0; i < 8; ++i){
        int row = rowbase + i*8 + rt;
        if (isA) row = (row < GM) ? row : (GM-1);
        gload16(sbase + (size_t)row*GK + k0 + kswz, &lds[cur^1][wave][i*8][0]);
      }
    }
#pragma unroll
    for (int ks = 0; ks < 2; ++ks){
      bf16x8 ah[2], al2[2], bh2[2], bl2[2];
#pragma unroll
      for (int i = 0; i < 2; ++i){
        int r = wm*32 + i*16 + rl;
        int sl = (ks*4 + kq) ^ (r & 7);
        ah[i]  = *(const bf16x8*)&lds[cur][0][r][sl*8];
        al2[i] = *(const bf16x8*)&lds[cur][1][r][sl*8];
      }
#pragma unroll
      for (int j = 0; j < 2; ++j){
        int cdx = wn*32 + j*16 + rl;
        int sl = (ks*4 + kq) ^ (cdx & 7);
        bh2[j] = *(const bf16x8*)&lds[cur][2][cdx][sl*8];
        bl2[j] = *(const bf16x8*)&lds[cur][3][cdx][sl*8];
      }
#pragma unroll
      for (int i = 0; i < 2; ++i){
#pragma unroll
        for (int j = 0; j < 2; ++j){
          acc[i][j] = __builtin_amdgcn_mfma_f32_16x16x32_bf16(ah[i],  bh2[j], acc[i][j], 0, 0, 0);
          acc[i][j] = __builtin_amdgcn_mfma_f32_16x16x32_bf16(ah[i],  bl2[j], acc[i][j], 0, 0, 0);
          acc[i][j] = __builtin_amdgcn_mfma_f32_16x16x32_bf16(al2[i], bh2[j], acc[i][j], 0, 0, 0);
        }
      }
    }
    __syncthreads();   // drains vmcnt (next buf staged) + lgkm (our ds_reads)
  }

#pragma unroll
  for (int i = 0; i < 2; ++i){
#pragma unroll
    for (int j = 0; j < 2; ++j){
      int col = bn*64 + wn*32 + j*16 + rl;
      float bb = b2[col];
#pragma unroll
      for (int r = 0; r < 4; ++r){
        int row = bm*64 + wm*32 + i*16 + kq*4 + r;
        if (row < GM) out[(size_t)row*GN + col] = 0.25f*acc[i][j][r] + bb;
      }
    }
  }
}

// ---------------------------------------------------------------------------
extern "C" void kernel_launch(void* const* d_in, const int* in_sizes, int n_in,
                              void* d_out, int out_size, void* d_ws, size_t ws_size,
                              hipStream_t stream){
  const int*   x     = (const int*)d_in[0];
  const int*   ei    = (const int*)d_in[1];
  const int*   ea    = (const int*)d_in[2];
  const float* x_emb = (const float*)d_in[3];
  const float* e_emb = (const float*)d_in[4];
  const float* W1    = (const float*)d_in[5];
  const float* as1   = (const float*)d_in[6];
  const float* ad1   = (const float*)d_in[7];
  const float* We1   = (const float*)d_in[8];
  const float* ae1   = (const float*)d_in[9];
  const float* b1    = (const float*)d_in[10];
  const float* W2    = (const float*)d_in[11];
  const float* as2   = (const float*)d_in[12];
  const float* ad2   = (const float*)d_in[13];
  const float* We2   = (const float*)d_in[14];
  const float* ae2   = (const float*)d_in[15];
  const float* b2    = (const float*)d_in[16];
  const int* srcv = ei;
  const int* dstv = ei + NE;
  float* out = (float*)d_out;

  char* p = (char*)d_ws;
  auto take = [&](size_t n){ void* q = (void*)p; p += (n + 255) & ~(size_t)255; return q; };
  int*   counts  = (int*)take(NN*4);
  int*   offsets = (int*)take((NN+1)*4);
  int*   cursor  = (int*)take(NN*4);
  int*   csr     = (int*)take(NE*4);
  float* wa_s1   = (float*)take(EMBD*NH*4);
  float* wa_d1   = (float*)take(EMBD*NH*4);
  float* we_a1   = (float*)take(EMBD*NH*4);
  float* wa_s2   = (float*)take(HID*NH*4);
  float* wa_d2   = (float*)take(HID*NH*4);
  float* we_a2   = (float*)take(EMBD*NH*4);
  float* xa_s1   = (float*)take(178*NH*4);
  float* xa_d1   = (float*)take(178*NH*4);
  float* ew1     = (float*)take(18*NH*4);
  float* ew2     = (float*)take(18*NH*4);
  float* xh1     = (float*)take((size_t)178*1536*4);
  float* parts1  = (float*)take((size_t)2*178*1536*4);
  unsigned short* Bth = (unsigned short*)take((size_t)GN*GK*2);
  unsigned short* Btl = (unsigned short*)take((size_t)GN*GK*2);
  unsigned short* Gh  = (unsigned short*)take((size_t)GM*GK*2);
  unsigned short* Gl  = (unsigned short*)take((size_t)GM*GK*2);
  int*   sa      = (int*)take(NE*4);
  int*   sb      = (int*)take(NE*4);
  float* eatt1   = (float*)take((size_t)NE*NH*4);
  float* eatt2   = (float*)take((size_t)NE*NH*4);
  float* hact    = (float*)take((size_t)NN*HID*4);
  float* asrc1   = (float*)take(NN*NH*4);
  float* adst1   = (float*)take(NN*NH*4);
  float* asrc2   = (float*)take(NN*NH*4);
  float* adst2   = (float*)take(NN*NH*4);

  // CSR (deterministic after in-bucket bitonic sort)
  k_zero<<<8, 256, 0, stream>>>(counts);
  k_count<<<(NE+255)/256, 256, 0, stream>>>(dstv, counts);
  k_scan<<<1, 1024, 0, stream>>>(counts, offsets, cursor);
  k_fill<<<(NE+255)/256, 256, 0, stream>>>(dstv, cursor, csr);
  k_sort<<<NN, 256, 0, stream>>>(offsets, csr);

  // prep
  k_prep1<<<10752, 64, 0, stream>>>(W1, as1, ad1, We1, ae1, W2, as2, ad2,
                                    We2, ae2, wa_s1, wa_d1, we_a1, wa_s2,
                                    wa_d2, we_a2);
  { dim3 g(GK/64, GN/64); k_bt<<<g, 256, 0, stream>>>(W2, Bth, Btl); }
  k_prep2<<<1568, 64, 0, stream>>>(x_emb, e_emb, wa_s1, wa_d1, we_a1, we_a2,
                                   xa_s1, xa_d1, ew1, ew2);

  // xh1 = x_emb @ W1 (split-K=2)
  { dim3 g(24, 6, 2); k_gemm1<<<g, 256, 0, stream>>>(x_emb, W1, parts1); }

  // fused elementwise (xh1 reduce, alpha terms, src pairs)
  k_misc<<<(S0+S1+S2+S3 + 255)/256, 256, 0, stream>>>(
      x, ea, srcv, parts1, xh1, xa_s1, xa_d1, ew1, ew2,
      asrc1, adst1, eatt1, eatt2, sa, sb);

  // layer 1 fused -> hact, asrc2, adst2
  k_gat1<<<NN, 384, 0, stream>>>(offsets, csr, srcv, sa, sb, x, asrc1, adst1,
                                 eatt1, xh1, b1, wa_s2, wa_d2, hact, asrc2, adst2);

  // layer 2 fused agg-first -> G (bf16 hi/lo)
  k_gat2<<<NN, 384, 0, stream>>>(offsets, csr, srcv, asrc2, adst2, eatt2, hact, Gh, Gl);

  // out = 0.25*(G @ Bt^T) + b2 via LDS-staged bf16 3-product MFMA
  k_mm2<<<384, 256, 0, stream>>>(Gh, Gl, Bth, Btl, b2, out);
}